// Round 5
// baseline (351.776 us; speedup 1.0000x reference)
//
#include <hip/hip_runtime.h>
#include <math.h>

#define HEADS 4
#define CH 64
#define HC 256   // HEADS*CH

typedef __attribute__((ext_vector_type(8))) short bf16x8;
typedef __attribute__((ext_vector_type(4))) float f32x4;

__device__ __forceinline__ float lrelu(float v) { return v > 0.f ? v : 0.2f * v; }

// fp32 -> bf16 bits, round-to-nearest-even
__device__ __forceinline__ unsigned int f2bf(float f) {
    unsigned int u = __float_as_uint(f);
    u += 0x7fffu + ((u >> 16) & 1u);
    return u >> 16;
}
__device__ __forceinline__ float bf2f(unsigned short u) {
    return __uint_as_float(((unsigned int)u) << 16);
}

__device__ __forceinline__ float4 wave_sum4(float4 v) {
#pragma unroll
    for (int m = 32; m; m >>= 1) {
        v.x += __shfl_xor(v.x, m);
        v.y += __shfl_xor(v.y, m);
        v.z += __shfl_xor(v.z, m);
        v.w += __shfl_xor(v.w, m);
    }
    return v;
}

// ---------------------------------------------------------------------------
// CSR build. XCD-affine replication kept (measured best), but 4 edges/thread
// via int4 loads (4x fewer threads/blocks), and self-loops handled WITHOUT
// atomics: scan uses deg+1, scan_add stores the self-loop in the last slot.
__global__ void count_kernel(const int* __restrict__ dst, int E, int vec_ok,
                             float scale8, int* __restrict__ deg) {
    int r = blockIdx.x & 7;
    int i = (blockIdx.x >> 3) * blockDim.x + threadIdx.x;
    int e0 = i * 4;
    if (e0 >= E) return;
    int d[4];
    int cnt;
    if (vec_ok && e0 + 3 < E) {
        int4 v = *(const int4*)(dst + e0);
        d[0] = v.x; d[1] = v.y; d[2] = v.z; d[3] = v.w; cnt = 4;
    } else {
        cnt = min(4, E - e0);
        for (int k = 0; k < cnt; ++k) d[k] = dst[e0 + k];
    }
    for (int k = 0; k < cnt; ++k) {
        int rr = min(7, (int)((float)d[k] * scale8));
        if (rr == r) atomicAdd(&deg[d[k]], 1);
    }
}

// scan pass 1 (+ float4-pack x: this grid is exactly N threads).
// NOTE: prefixes deg[g]+1 — the +1 is the implicit self-loop.
__global__ void scan_blocks(const int* __restrict__ deg,
                            int* __restrict__ off,
                            int* __restrict__ bsum,
                            const float* __restrict__ x,
                            float4* __restrict__ xq, int N) {
    __shared__ int sh[256];
    int t = threadIdx.x;
    int g = blockIdx.x * 256 + t;
    int v = (g < N) ? deg[g] + 1 : 0;
    if (g < N) xq[g] = make_float4(x[3 * g], x[3 * g + 1], x[3 * g + 2], 0.f);
    sh[t] = v;
    __syncthreads();
    for (int d = 1; d < 256; d <<= 1) {
        int xv = (t >= d) ? sh[t - d] : 0;
        __syncthreads();
        sh[t] += xv;
        __syncthreads();
    }
    if (g < N) off[g] = sh[t] - v;
    if (t == 255) bsum[blockIdx.x] = sh[255];
}

__global__ void scan_bsums(int* __restrict__ bsum, int G,
                           int* __restrict__ total_out) {
    __shared__ int sh[256];
    int t = threadIdx.x;
    int chunk = (G + 255) / 256;
    int lo = t * chunk, hi = min(lo + chunk, G);
    int s = 0;
    for (int i = lo; i < hi; ++i) s += bsum[i];
    sh[t] = s;
    __syncthreads();
    for (int d = 1; d < 256; d <<= 1) {
        int xv = (t >= d) ? sh[t - d] : 0;
        __syncthreads();
        sh[t] += xv;
        __syncthreads();
    }
    int run = (t > 0) ? sh[t - 1] : 0;
    for (int i = lo; i < hi; ++i) { int v = bsum[i]; bsum[i] = run; run += v; }
    if (t == 255) *total_out = sh[255];
}

// scan pass 3 + plain-store self-loop into the node's LAST slot
// (slots [off, off+deg) are filled by scatter via cursor; slot off+deg = self).
__global__ void scan_add(int* __restrict__ off, const int* __restrict__ bsum,
                         const int* __restrict__ deg,
                         int* __restrict__ csr_src, int N) {
    int g = blockIdx.x * 256 + threadIdx.x;
    if (g < N) {
        int o = off[g] + bsum[blockIdx.x];
        off[g] = o;
        csr_src[o + deg[g]] = g;
    }
}

__global__ void scatter_kernel(const int* __restrict__ src,
                               const int* __restrict__ dst, int E, int vec_ok,
                               float scale8,
                               const int* __restrict__ off,
                               int* __restrict__ cursor,
                               int* __restrict__ csr_src) {
    int r = blockIdx.x & 7;
    int i = (blockIdx.x >> 3) * blockDim.x + threadIdx.x;
    int e0 = i * 4;
    if (e0 >= E) return;
    int s[4], d[4];
    int cnt;
    if (vec_ok && e0 + 3 < E) {
        int4 sv = *(const int4*)(src + e0);
        int4 dv = *(const int4*)(dst + e0);
        s[0] = sv.x; s[1] = sv.y; s[2] = sv.z; s[3] = sv.w;
        d[0] = dv.x; d[1] = dv.y; d[2] = dv.z; d[3] = dv.w; cnt = 4;
    } else {
        cnt = min(4, E - e0);
        for (int k = 0; k < cnt; ++k) { s[k] = src[e0 + k]; d[k] = dst[e0 + k]; }
    }
    for (int k = 0; k < cnt; ++k) {
        int rr = min(7, (int)((float)d[k] * scale8));
        if (rr != r) continue;
        int p = atomicAdd(&cursor[d[k]], 1);
        csr_src[off[d[k]] + p] = s[k];
    }
}

// ---------------------------------------------------------------------------
// ALL weight prep in one launch.
__device__ __forceinline__ void prep_blk(int b, int t, const float* W,
                                         const float* a_s, const float* a_d,
                                         unsigned short* Wb, float* ws,
                                         float* wd) {
    if (b < 64) {
        Wb[b * 256 + t] = (unsigned short)f2bf(W[(t >> 2) * HC + (t & 3) * CH + b]);
    } else {
        int idx = (b - 64) * 256 + t;      // 0..511
        int which = idx >= 256;
        int i = which ? idx - 256 : idx;   // i = k*4+h
        int k = i >> 2, h = i & 3;
        const float* av = (which ? a_d : a_s) + h * CH;
        const float* Wr = W + (size_t)k * HC + h * CH;
        float s = 0.f;
        for (int c = 0; c < CH; ++c) s += Wr[c] * av[c];
        (which ? wd : ws)[i] = s;
    }
}

__global__ void prep_all(const float* __restrict__ W1,
                         const float* __restrict__ a1s,
                         const float* __restrict__ a1d,
                         float* __restrict__ ws1, float* __restrict__ wd1,
                         const float* __restrict__ W2,
                         const float* __restrict__ a2s,
                         const float* __restrict__ a2d,
                         unsigned short* __restrict__ Wb2,
                         float* __restrict__ ws2, float* __restrict__ wd2,
                         const float* __restrict__ W3,
                         const float* __restrict__ a3s,
                         const float* __restrict__ a3d,
                         unsigned short* __restrict__ Wb3,
                         float* __restrict__ ws3, float* __restrict__ wd3) {
    int b = blockIdx.x, t = threadIdx.x;
    if (b < 66) {
        prep_blk(b, t, W2, a2s, a2d, Wb2, ws2, wd2);
    } else if (b < 132) {
        prep_blk(b - 66, t, W3, a3s, a3d, Wb3, ws3, wd3);
    } else {
        for (int idx = t; idx < 24; idx += blockDim.x) {
            int which = idx >= 12;
            int i = which ? idx - 12 : idx;
            int k = i >> 2, h = i & 3;
            const float* av = (which ? a1d : a1s) + h * CH;
            const float* Wr = W1 + (size_t)k * HC + h * CH;
            float s = 0.f;
            for (int c = 0; c < CH; ++c) s += Wr[c] * av[c];
            (which ? wd1 : ws1)[i] = s;
        }
    }
}

// ---------------------------------------------------------------------------
// Layer-1 aggregation: 4 LANES per node (round-4's thread-per-node had only
// 781 waves total — zero TLP; this gives 3125 waves + float4 x loads).
__global__ void fused1_kernel(const int* __restrict__ off,
                              const int* __restrict__ csr_src,
                              const float4* __restrict__ xq,
                              const float* __restrict__ ws,   // ws1[12], k*4+h
                              const float* __restrict__ wd,   // wd1[12]
                              float4* __restrict__ zl, int N) {
    int t = blockIdx.x * blockDim.x + threadIdx.x;
    int n = t >> 2, j = t & 3;
    if (n >= N) return;
    float4 xn = xq[n];
    float ad0 = xn.x * wd[0] + xn.y * wd[4] + xn.z * wd[8];
    float ad1 = xn.x * wd[1] + xn.y * wd[5] + xn.z * wd[9];
    float ad2 = xn.x * wd[2] + xn.y * wd[6] + xn.z * wd[10];
    float ad3 = xn.x * wd[3] + xn.y * wd[7] + xn.z * wd[11];

    int o0 = off[n], o1 = off[n + 1];
    float z[12];
#pragma unroll
    for (int q = 0; q < 12; ++q) z[q] = 0.f;
    float l0 = 0.f, l1 = 0.f, l2 = 0.f, l3 = 0.f;

    for (int i = o0 + j; i < o1; i += 4) {
        int s = csr_src[i];
        float4 xv = xq[s];
        float e0 = __expf(lrelu(xv.x * ws[0] + xv.y * ws[4] + xv.z * ws[8]  + ad0));
        float e1 = __expf(lrelu(xv.x * ws[1] + xv.y * ws[5] + xv.z * ws[9]  + ad1));
        float e2 = __expf(lrelu(xv.x * ws[2] + xv.y * ws[6] + xv.z * ws[10] + ad2));
        float e3 = __expf(lrelu(xv.x * ws[3] + xv.y * ws[7] + xv.z * ws[11] + ad3));
        l0 += e0; l1 += e1; l2 += e2; l3 += e3;
        z[0] += e0 * xv.x; z[1]  += e0 * xv.y; z[2]  += e0 * xv.z;
        z[3] += e1 * xv.x; z[4]  += e1 * xv.y; z[5]  += e1 * xv.z;
        z[6] += e2 * xv.x; z[7]  += e2 * xv.y; z[8]  += e2 * xv.z;
        z[9] += e3 * xv.x; z[10] += e3 * xv.y; z[11] += e3 * xv.z;
    }
    // reduce across the 4 lanes of this node
#pragma unroll
    for (int m = 1; m < 4; m <<= 1) {
#pragma unroll
        for (int q = 0; q < 12; ++q) z[q] += __shfl_xor(z[q], m);
        l0 += __shfl_xor(l0, m);
        l1 += __shfl_xor(l1, m);
        l2 += __shfl_xor(l2, m);
        l3 += __shfl_xor(l3, m);
    }
    if (j == 0) {
        zl[(size_t)n * 4 + 0] = make_float4(z[0], z[1], z[2], z[3]);
        zl[(size_t)n * 4 + 1] = make_float4(z[4], z[5], z[6], z[7]);
        zl[(size_t)n * 4 + 2] = make_float4(z[8], z[9], z[10], z[11]);
        zl[(size_t)n * 4 + 3] = make_float4(l0, l1, l2, l3);
    }
}

// Layer-1 epilogue: fp32 out + packed bf16 rows + FOLDED layer-2 logits.
__global__ void epi1_kernel(const float4* __restrict__ zl,
                            const float* __restrict__ W1,
                            const float* __restrict__ b1,
                            const float4* __restrict__ ws2_4,
                            const float4* __restrict__ wd2_4,
                            float4* __restrict__ asrc4,
                            float4* __restrict__ adst4,
                            float* __restrict__ out,
                            unsigned short* __restrict__ out_pack, int N) {
    int node = (blockIdx.x * blockDim.x + threadIdx.x) >> 6;
    int c = threadIdx.x & 63;
    if (node >= N) return;
    float4 z0 = zl[(size_t)node * 4 + 0];
    float4 z1 = zl[(size_t)node * 4 + 1];
    float4 z2 = zl[(size_t)node * 4 + 2];
    float4 l4 = zl[(size_t)node * 4 + 3];
    float i0 = 0.25f / l4.x, i1 = 0.25f / l4.y;
    float i2 = 0.25f / l4.z, i3 = 0.25f / l4.w;
    float acc =
        (z0.x * W1[0 * HC +   0 + c] + z0.y * W1[1 * HC +   0 + c] + z0.z * W1[2 * HC +   0 + c]) * i0 +
        (z0.w * W1[0 * HC +  64 + c] + z1.x * W1[1 * HC +  64 + c] + z1.y * W1[2 * HC +  64 + c]) * i1 +
        (z1.z * W1[0 * HC + 128 + c] + z1.w * W1[1 * HC + 128 + c] + z2.x * W1[2 * HC + 128 + c]) * i2 +
        (z2.y * W1[0 * HC + 192 + c] + z2.z * W1[1 * HC + 192 + c] + z2.w * W1[2 * HC + 192 + c]) * i3;
    float v = acc + b1[c];
    v = v > 0.f ? v : expm1f(v);
    out[(size_t)node * CH + c] = v;
    out_pack[(size_t)node * CH + c] = (unsigned short)f2bf(v);
    float4 wsv = ws2_4[c], wdv = wd2_4[c];
    float4 sacc = make_float4(v * wsv.x, v * wsv.y, v * wsv.z, v * wsv.w);
    float4 dacc = make_float4(v * wdv.x, v * wdv.y, v * wdv.z, v * wdv.w);
    sacc = wave_sum4(sacc);
    dacc = wave_sum4(dacc);
    if (c == 0) { asrc4[node] = sacc; adst4[node] = dacc; }
}

// ---------------------------------------------------------------------------
// Layers 2/3 fused (round-2 parallelism-fixed structure, measured <=43.8us):
// 512-thread block = 8 waves / 32 nodes; stage A = each wave aggregates 4
// nodes; stage B = waves 0-1 run the two 16-row MFMA tiles + epilogue.
// Logit in/out buffers must be different (A-set / B-set double buffer).
__global__ __launch_bounds__(512) void layer_fused(
                            const int* __restrict__ off,
                            const int* __restrict__ csr_src,
                            const unsigned short* __restrict__ xp,
                            const float4* __restrict__ asrc4,
                            const float4* __restrict__ adst4,
                            const unsigned short* __restrict__ Wb,
                            const float* __restrict__ bias,
                            const float* __restrict__ residual,
                            const float4* __restrict__ wsn4,
                            const float4* __restrict__ wdn4,
                            float4* __restrict__ oasrc4,
                            float4* __restrict__ oadst4,
                            const float* __restrict__ lin_w,
                            const float* __restrict__ lin_b,
                            float* __restrict__ out_f32,
                            unsigned short* __restrict__ out_pack,
                            float* __restrict__ out_final, int N) {
    __shared__ unsigned short zs[32][256];   // 16KB, row = node-in-block
    __shared__ float4 exs[8][64];            // 8KB
    __shared__ unsigned int sss[8][64];      // 2KB

    int w = threadIdx.x >> 6;      // 0..7
    int lane = threadIdx.x & 63;
    const char* xpb = (const char*)xp + lane * 2;
    char* zbase = (char*)zs;

    // ---- stage A: each wave aggregates its 4 nodes ----
    for (int ii = 0; ii < 4; ++ii) {
        int rloc = w * 4 + ii;               // 0..31
        int node = blockIdx.x * 32 + rloc;
        if (node < N) {
            int o0 = off[node], o1 = off[node + 1];
            int deg = o1 - o0;
            float4 ad = adst4[node];
            float l0 = 0.f, l1 = 0.f, l2 = 0.f, l3 = 0.f;
            float z0 = 0.f, z1 = 0.f, z2 = 0.f, z3 = 0.f;
            for (int base = 0; base < deg; base += 64) {
                int i = base + lane;
                int s = 0;
                float4 ev = make_float4(-INFINITY, -INFINITY, -INFINITY, -INFINITY);
                if (i < deg) {
                    s = csr_src[o0 + i];
                    float4 as = asrc4[s];
                    ev.x = lrelu(as.x + ad.x);
                    ev.y = lrelu(as.y + ad.y);
                    ev.z = lrelu(as.z + ad.z);
                    ev.w = lrelu(as.w + ad.w);
                }
                float4 ex;
                ex.x = __expf(ev.x);   // inactive lanes: exp(-inf) = 0
                ex.y = __expf(ev.y);
                ex.z = __expf(ev.z);
                ex.w = __expf(ev.w);
                float4 ls = wave_sum4(ex);
                l0 += ls.x; l1 += ls.y; l2 += ls.z; l3 += ls.w;
                exs[w][lane] = ex;
                sss[w][lane] = (unsigned)s * 128u;
                int cnt = min(64, deg - base);
#pragma unroll 4
                for (int e = 0; e < cnt; ++e) {
                    unsigned soff = sss[w][e];
                    float4 exe = exs[w][e];
                    float xk = bf2f(*(const unsigned short*)(xpb + soff));
                    z0 += exe.x * xk; z1 += exe.y * xk;
                    z2 += exe.z * xk; z3 += exe.w * xk;
                }
            }
            float s0 = 0.25f / l0, s1 = 0.25f / l1;
            float s2 = 0.25f / l2, s3 = 0.25f / l3;
            uint2 zo;
            zo.x = f2bf(z0 * s0) | (f2bf(z1 * s1) << 16);
            zo.y = f2bf(z2 * s2) | (f2bf(z3 * s3) << 16);
            // row rloc, swizzle byte-in-row by ((rloc&7)<<4)
            *(uint2*)(zbase + (size_t)rloc * 512 +
                      (((unsigned)lane * 8u) ^ ((unsigned)(rloc & 7) << 4))) = zo;
        }
    }

    __syncthreads();
    if (w >= 2) return;

    // ---- stage B: MFMA tiles (wave 0 -> rows 0-15, wave 1 -> rows 16-31) ----
    int quad = lane >> 4, col = lane & 15;
    int nbase = blockIdx.x * 32 + w * 16;

    f32x4 zero4 = {0.f, 0.f, 0.f, 0.f};
    f32x4 acc[4];
#pragma unroll
    for (int t = 0; t < 4; ++t) acc[t] = zero4;

    // row = w*16+col; (row&7) == (col&7) since w*16 is a multiple of 8
    const char* abase = (const char*)zs + (size_t)(w * 16 + col) * 512;
    unsigned aswz = (unsigned)((col & 7) << 4);
#pragma unroll
    for (int q = 0; q < 8; ++q) {
        bf16x8 af = *(const bf16x8*)(abase + (((unsigned)(quad * 16 + q * 64)) ^ aswz));
#pragma unroll
        for (int t = 0; t < 4; ++t) {
            const unsigned short* bp = Wb + (size_t)(t * 16 + col) * HC + q * 32 + quad * 8;
            bf16x8 bfrag = *(const bf16x8*)bp;
            acc[t] = __builtin_amdgcn_mfma_f32_16x16x32_bf16(af, bfrag, acc[t], 0, 0, 0);
        }
    }

    if (!out_final) {
        float vv[4][4];   // [t][r]
#pragma unroll
        for (int t = 0; t < 4; ++t) {
            int c = t * 16 + col;
            float bc = bias[c];
#pragma unroll
            for (int r = 0; r < 4; ++r) {
                int n = nbase + quad * 4 + r;
                float v = acc[t][r] + bc;
                v = v > 0.f ? v : expm1f(v);
                v += residual[(size_t)n * CH + c];
                vv[t][r] = v;
                if (n < N) {
                    out_f32[(size_t)n * CH + c] = v;
                    out_pack[(size_t)n * CH + c] = (unsigned short)f2bf(v);
                }
            }
        }
        float4 wsv[4], wdv[4];
#pragma unroll
        for (int t = 0; t < 4; ++t) { wsv[t] = wsn4[t * 16 + col]; wdv[t] = wdn4[t * 16 + col]; }
#pragma unroll
        for (int r = 0; r < 4; ++r) {
            int n = nbase + quad * 4 + r;
            float4 sa = make_float4(0.f, 0.f, 0.f, 0.f);
            float4 da = make_float4(0.f, 0.f, 0.f, 0.f);
#pragma unroll
            for (int t = 0; t < 4; ++t) {
                float v = vv[t][r];
                sa.x += v * wsv[t].x; sa.y += v * wsv[t].y;
                sa.z += v * wsv[t].z; sa.w += v * wsv[t].w;
                da.x += v * wdv[t].x; da.y += v * wdv[t].y;
                da.z += v * wdv[t].z; da.w += v * wdv[t].w;
            }
#pragma unroll
            for (int m = 8; m; m >>= 1) {
                sa.x += __shfl_xor(sa.x, m); sa.y += __shfl_xor(sa.y, m);
                sa.z += __shfl_xor(sa.z, m); sa.w += __shfl_xor(sa.w, m);
                da.x += __shfl_xor(da.x, m); da.y += __shfl_xor(da.y, m);
                da.z += __shfl_xor(da.z, m); da.w += __shfl_xor(da.w, m);
            }
            if (col == 0 && n < N) { oasrc4[n] = sa; oadst4[n] = da; }
        }
    } else {
        float lw[4], bb[4];
#pragma unroll
        for (int t = 0; t < 4; ++t) { lw[t] = lin_w[t * 16 + col]; bb[t] = bias[t * 16 + col]; }
#pragma unroll
        for (int r = 0; r < 4; ++r) {
            int n = nbase + quad * 4 + r;
            float ts = 0.f;
#pragma unroll
            for (int t = 0; t < 4; ++t) {
                float v = acc[t][r] + bb[t];
                v = v > 0.f ? v : expm1f(v);
                v += residual[(size_t)n * CH + (t * 16 + col)];
                ts += v * lw[t];
            }
            ts += __shfl_xor(ts, 1);
            ts += __shfl_xor(ts, 2);
            ts += __shfl_xor(ts, 4);
            ts += __shfl_xor(ts, 8);
            if (col == 0 && n < N) out_final[n] = ts + lin_b[0];
        }
    }
}

// ---------------------------------------------------------------------------
extern "C" void kernel_launch(void* const* d_in, const int* in_sizes, int n_in,
                              void* d_out, int out_size, void* d_ws, size_t ws_size,
                              hipStream_t stream) {
    const float* x      = (const float*)d_in[0];
    const int*   ei     = (const int*)  d_in[1];
    const float* W1     = (const float*)d_in[2];
    const float* a1s    = (const float*)d_in[3];
    const float* a1d    = (const float*)d_in[4];
    const float* b1     = (const float*)d_in[5];
    const float* W2     = (const float*)d_in[6];
    const float* a2s    = (const float*)d_in[7];
    const float* a2d    = (const float*)d_in[8];
    const float* b2     = (const float*)d_in[9];
    const float* W3     = (const float*)d_in[10];
    const float* a3s    = (const float*)d_in[11];
    const float* a3d    = (const float*)d_in[12];
    const float* b3     = (const float*)d_in[13];
    const float* lin_w  = (const float*)d_in[14];
    const float* lin_b  = (const float*)d_in[15];

    const int N = in_sizes[0] / 3;
    const int E = in_sizes[1] / 2;
    const int Et = E + N;
    const int* src = ei;
    const int* dst = ei + E;
    const float scale8 = 8.0f / (float)N;
    const int vec_ok = ((((size_t)src | (size_t)dst) & 15) == 0) ? 1 : 0;

    // ---- workspace layout (xq first for 16B alignment) ----
    float* xq_f   = (float*)d_ws;                         // N*4 (float4)
    unsigned short* xpA = (unsigned short*)(xq_f + (size_t)N * 4);  // N*64
    unsigned short* xpB = xpA + (size_t)N * CH;           // N*64
    unsigned short* Wb2 = xpB + (size_t)N * CH;           // 16384
    unsigned short* Wb3 = Wb2 + 16384;                    // 16384
    float* bufA   = (float*)(Wb3 + 16384);                // N*64
    float* bufB   = bufA + (size_t)N * CH;                // N*64
    float* zl     = bufB + (size_t)N * CH;                // N*16
    float* asrcA  = zl   + (size_t)N * 16;                // N*4
    float* adstA  = asrcA + (size_t)N * 4;                // N*4
    float* asrcB  = adstA + (size_t)N * 4;                // N*4
    float* adstB  = asrcB + (size_t)N * 4;                // N*4
    float* ws1    = adstB + (size_t)N * 4;                // 16
    float* wd1    = ws1 + 16;                             // 16
    float* ws2    = wd1 + 16;                             // 256
    float* wd2    = ws2 + 256;                            // 256
    float* ws3    = wd2 + 256;                            // 256
    float* wd3    = ws3 + 256;                            // 256
    int* deg      = (int*)(wd3 + 256);                    // N
    int* cursor   = deg + N;                              // N (adjacent: 1 memset)
    int* off      = cursor + N;                           // N+4
    int* bsum     = off + N + 4;                          // 256
    int* csr_src  = bsum + 256;                           // Et

    const int B = 256;
    const int G = (N + 255) / 256;
    const int EB4 = (E + 3) / 4;                 // 4 edges per thread
    const int CB = (EB4 + B - 1) / B;

    // ---- CSR build ----
    hipMemsetAsync(deg, 0, (size_t)2 * N * sizeof(int), stream);  // deg+cursor
    count_kernel<<<CB * 8, B, 0, stream>>>(dst, E, vec_ok, scale8, deg);
    scan_blocks<<<G, B, 0, stream>>>(deg, off, bsum, x, (float4*)xq_f, N);
    scan_bsums<<<1, B, 0, stream>>>(bsum, G, off + N);
    scan_add<<<G, B, 0, stream>>>(off, bsum, deg, csr_src, N);
    scatter_kernel<<<CB * 8, B, 0, stream>>>(src, dst, E, vec_ok, scale8,
                                             off, cursor, csr_src);

    // ---- all weight prep in one launch ----
    prep_all<<<133, B, 0, stream>>>(W1, a1s, a1d, ws1, wd1,
                                    W2, a2s, a2d, Wb2, ws2, wd2,
                                    W3, a3s, a3d, Wb3, ws3, wd3);

    int nwave_blocks = (N * 64 + B - 1) / B;   // wave per node (epi1)
    int nfused_blocks = (N + 31) / 32;         // 32 nodes per 512-thread block

    // ---- Layer 1 ----
    fused1_kernel<<<(N * 4 + B - 1) / B, B, 0, stream>>>(
        off, csr_src, (const float4*)xq_f, ws1, wd1, (float4*)zl, N);
    epi1_kernel<<<nwave_blocks, B, 0, stream>>>(
        (const float4*)zl, W1, b1, (const float4*)ws2, (const float4*)wd2,
        (float4*)asrcA, (float4*)adstA, bufA, xpA, N);

    // ---- Layer 2 (agg+GEMM fused; epilogue folds layer-3 logits -> B set) ----
    layer_fused<<<nfused_blocks, 512, 0, stream>>>(
        off, csr_src, xpA, (const float4*)asrcA, (const float4*)adstA,
        Wb2, b2, bufA, (const float4*)ws3, (const float4*)wd3,
        (float4*)asrcB, (float4*)adstB,
        nullptr, nullptr, bufB, xpB, nullptr, N);

    // ---- Layer 3 (agg+GEMM fused + final linear) ----
    layer_fused<<<nfused_blocks, 512, 0, stream>>>(
        off, csr_src, xpB, (const float4*)asrcB, (const float4*)adstB,
        Wb3, b3, bufB, nullptr, nullptr,
        nullptr, nullptr,
        lin_w, lin_b, nullptr, nullptr, (float*)d_out, N);
}

// Round 6
// 344.473 us; speedup vs baseline: 1.0212x; 1.0212x over previous
//
#include <hip/hip_runtime.h>
#include <math.h>

#define HEADS 4
#define CH 64
#define HC 256   // HEADS*CH

typedef __attribute__((ext_vector_type(8))) short bf16x8;
typedef __attribute__((ext_vector_type(4))) float f32x4;

__device__ __forceinline__ float lrelu(float v) { return v > 0.f ? v : 0.2f * v; }

// fp32 -> bf16 bits, round-to-nearest-even
__device__ __forceinline__ unsigned int f2bf(float f) {
    unsigned int u = __float_as_uint(f);
    u += 0x7fffu + ((u >> 16) & 1u);
    return u >> 16;
}
__device__ __forceinline__ float bf2f(unsigned short u) {
    return __uint_as_float(((unsigned int)u) << 16);
}

__device__ __forceinline__ float4 wave_sum4(float4 v) {
#pragma unroll
    for (int m = 32; m; m >>= 1) {
        v.x += __shfl_xor(v.x, m);
        v.y += __shfl_xor(v.y, m);
        v.z += __shfl_xor(v.z, m);
        v.w += __shfl_xor(v.w, m);
    }
    return v;
}

// ---------------------------------------------------------------------------
// CSR build. XCD-affine replication, 4 edges/thread via int4; self-loops
// handled WITHOUT atomics (scan prefixes deg+1, scan_add plain-stores the
// self-loop into the node's last slot).
__global__ void count_kernel(const int* __restrict__ dst, int E, int vec_ok,
                             float scale8, int* __restrict__ deg) {
    int r = blockIdx.x & 7;
    int i = (blockIdx.x >> 3) * blockDim.x + threadIdx.x;
    int e0 = i * 4;
    if (e0 >= E) return;
    int d[4];
    int cnt;
    if (vec_ok && e0 + 3 < E) {
        int4 v = *(const int4*)(dst + e0);
        d[0] = v.x; d[1] = v.y; d[2] = v.z; d[3] = v.w; cnt = 4;
    } else {
        cnt = min(4, E - e0);
        for (int k = 0; k < cnt; ++k) d[k] = dst[e0 + k];
    }
    for (int k = 0; k < cnt; ++k) {
        int rr = min(7, (int)((float)d[k] * scale8));
        if (rr == r) atomicAdd(&deg[d[k]], 1);
    }
}

// scan pass 1 (+ float4-pack x: this grid is exactly N threads).
__global__ void scan_blocks(const int* __restrict__ deg,
                            int* __restrict__ off,
                            int* __restrict__ bsum,
                            const float* __restrict__ x,
                            float4* __restrict__ xq, int N) {
    __shared__ int sh[256];
    int t = threadIdx.x;
    int g = blockIdx.x * 256 + t;
    int v = (g < N) ? deg[g] + 1 : 0;
    if (g < N) xq[g] = make_float4(x[3 * g], x[3 * g + 1], x[3 * g + 2], 0.f);
    sh[t] = v;
    __syncthreads();
    for (int d = 1; d < 256; d <<= 1) {
        int xv = (t >= d) ? sh[t - d] : 0;
        __syncthreads();
        sh[t] += xv;
        __syncthreads();
    }
    if (g < N) off[g] = sh[t] - v;
    if (t == 255) bsum[blockIdx.x] = sh[255];
}

__global__ void scan_bsums(int* __restrict__ bsum, int G,
                           int* __restrict__ total_out) {
    __shared__ int sh[256];
    int t = threadIdx.x;
    int chunk = (G + 255) / 256;
    int lo = t * chunk, hi = min(lo + chunk, G);
    int s = 0;
    for (int i = lo; i < hi; ++i) s += bsum[i];
    sh[t] = s;
    __syncthreads();
    for (int d = 1; d < 256; d <<= 1) {
        int xv = (t >= d) ? sh[t - d] : 0;
        __syncthreads();
        sh[t] += xv;
        __syncthreads();
    }
    int run = (t > 0) ? sh[t - 1] : 0;
    for (int i = lo; i < hi; ++i) { int v = bsum[i]; bsum[i] = run; run += v; }
    if (t == 255) *total_out = sh[255];
}

// scan pass 3 + plain-store self-loop into the node's LAST slot.
__global__ void scan_add(int* __restrict__ off, const int* __restrict__ bsum,
                         const int* __restrict__ deg,
                         int* __restrict__ csr_src, int N) {
    int g = blockIdx.x * 256 + threadIdx.x;
    if (g < N) {
        int o = off[g] + bsum[blockIdx.x];
        off[g] = o;
        csr_src[o + deg[g]] = g;
    }
}

__global__ void scatter_kernel(const int* __restrict__ src,
                               const int* __restrict__ dst, int E, int vec_ok,
                               float scale8,
                               const int* __restrict__ off,
                               int* __restrict__ cursor,
                               int* __restrict__ csr_src) {
    int r = blockIdx.x & 7;
    int i = (blockIdx.x >> 3) * blockDim.x + threadIdx.x;
    int e0 = i * 4;
    if (e0 >= E) return;
    int s[4], d[4];
    int cnt;
    if (vec_ok && e0 + 3 < E) {
        int4 sv = *(const int4*)(src + e0);
        int4 dv = *(const int4*)(dst + e0);
        s[0] = sv.x; s[1] = sv.y; s[2] = sv.z; s[3] = sv.w;
        d[0] = dv.x; d[1] = dv.y; d[2] = dv.z; d[3] = dv.w; cnt = 4;
    } else {
        cnt = min(4, E - e0);
        for (int k = 0; k < cnt; ++k) { s[k] = src[e0 + k]; d[k] = dst[e0 + k]; }
    }
    for (int k = 0; k < cnt; ++k) {
        int rr = min(7, (int)((float)d[k] * scale8));
        if (rr != r) continue;
        int p = atomicAdd(&cursor[d[k]], 1);
        csr_src[off[d[k]] + p] = s[k];
    }
}

// ---------------------------------------------------------------------------
// ALL weight prep in one launch.
__device__ __forceinline__ void prep_blk(int b, int t, const float* W,
                                         const float* a_s, const float* a_d,
                                         unsigned short* Wb, float* ws,
                                         float* wd) {
    if (b < 64) {
        Wb[b * 256 + t] = (unsigned short)f2bf(W[(t >> 2) * HC + (t & 3) * CH + b]);
    } else {
        int idx = (b - 64) * 256 + t;      // 0..511
        int which = idx >= 256;
        int i = which ? idx - 256 : idx;   // i = k*4+h
        int k = i >> 2, h = i & 3;
        const float* av = (which ? a_d : a_s) + h * CH;
        const float* Wr = W + (size_t)k * HC + h * CH;
        float s = 0.f;
        for (int c = 0; c < CH; ++c) s += Wr[c] * av[c];
        (which ? wd : ws)[i] = s;
    }
}

__global__ void prep_all(const float* __restrict__ W1,
                         const float* __restrict__ a1s,
                         const float* __restrict__ a1d,
                         float* __restrict__ ws1, float* __restrict__ wd1,
                         const float* __restrict__ W2,
                         const float* __restrict__ a2s,
                         const float* __restrict__ a2d,
                         unsigned short* __restrict__ Wb2,
                         float* __restrict__ ws2, float* __restrict__ wd2,
                         const float* __restrict__ W3,
                         const float* __restrict__ a3s,
                         const float* __restrict__ a3d,
                         unsigned short* __restrict__ Wb3,
                         float* __restrict__ ws3, float* __restrict__ wd3) {
    int b = blockIdx.x, t = threadIdx.x;
    if (b < 66) {
        prep_blk(b, t, W2, a2s, a2d, Wb2, ws2, wd2);
    } else if (b < 132) {
        prep_blk(b - 66, t, W3, a3s, a3d, Wb3, ws3, wd3);
    } else {
        for (int idx = t; idx < 24; idx += blockDim.x) {
            int which = idx >= 12;
            int i = which ? idx - 12 : idx;
            int k = i >> 2, h = i & 3;
            const float* av = (which ? a1d : a1s) + h * CH;
            const float* Wr = W1 + (size_t)k * HC + h * CH;
            float s = 0.f;
            for (int c = 0; c < CH; ++c) s += Wr[c] * av[c];
            (which ? wd1 : ws1)[i] = s;
        }
    }
}

// ---------------------------------------------------------------------------
// Input-space aggregation (layers 2/3): wave per dst node, lane = k (0..63).
__global__ void agg_kernel(const int* __restrict__ off,
                           const int* __restrict__ csr_src,
                           const unsigned short* __restrict__ xp,
                           const float4* __restrict__ asrc4,
                           const float4* __restrict__ adst4,
                           uint2* __restrict__ zb2, int N) {
    __shared__ float4 exs[4][64];
    __shared__ unsigned int sss[4][64];
    int node = (blockIdx.x * blockDim.x + threadIdx.x) >> 6;
    int w = (threadIdx.x >> 6) & 3;
    int lane = threadIdx.x & 63;
    if (node >= N) return;
    int o0 = off[node], o1 = off[node + 1];
    int deg = o1 - o0;
    float4 ad = adst4[node];

    float l0 = 0.f, l1 = 0.f, l2 = 0.f, l3 = 0.f;
    float z0 = 0.f, z1 = 0.f, z2 = 0.f, z3 = 0.f;
    const char* xpb = (const char*)xp + lane * 2;

    for (int base = 0; base < deg; base += 64) {
        int i = base + lane;
        int s = 0;
        float4 ev = make_float4(-INFINITY, -INFINITY, -INFINITY, -INFINITY);
        if (i < deg) {
            s = csr_src[o0 + i];
            float4 as = asrc4[s];
            ev.x = lrelu(as.x + ad.x);
            ev.y = lrelu(as.y + ad.y);
            ev.z = lrelu(as.z + ad.z);
            ev.w = lrelu(as.w + ad.w);
        }
        float4 ex;
        ex.x = __expf(ev.x);   // inactive lanes: exp(-inf) = 0
        ex.y = __expf(ev.y);
        ex.z = __expf(ev.z);
        ex.w = __expf(ev.w);
        float4 ls = wave_sum4(ex);
        l0 += ls.x; l1 += ls.y; l2 += ls.z; l3 += ls.w;
        exs[w][lane] = ex;
        sss[w][lane] = (unsigned)s * 128u;   // byte offset of row s in xp

        int cnt = min(64, deg - base);
#pragma unroll 4
        for (int e = 0; e < cnt; ++e) {
            unsigned soff = sss[w][e];
            float4 exe = exs[w][e];
            float xk = bf2f(*(const unsigned short*)(xpb + soff));
            z0 += exe.x * xk; z1 += exe.y * xk;
            z2 += exe.z * xk; z3 += exe.w * xk;
        }
    }
    float s0 = 0.25f / l0, s1 = 0.25f / l1, s2 = 0.25f / l2, s3 = 0.25f / l3;
    uint2 zo;
    zo.x = f2bf(z0 * s0) | (f2bf(z1 * s1) << 16);
    zo.y = f2bf(z2 * s2) | (f2bf(z3 * s3) << 16);
    zb2[(size_t)node * CH + lane] = zo;
}

// ---------------------------------------------------------------------------
// MFMA post-aggregation GEMM (layers 2/3). A = zb (bf16 [n][j], j=k*4+h),
// B = Wb (bf16 [c][j]).  Layer-2 epilogue folds layer-3 logits; layer 3
// folds the final linear.
__global__ void gemm_mfma(const unsigned short* __restrict__ zb,
                          const unsigned short* __restrict__ Wb,
                          const float* __restrict__ bias,
                          const float* __restrict__ residual,
                          const float4* __restrict__ wsn4,
                          const float4* __restrict__ wdn4,
                          float4* __restrict__ asrc4,
                          float4* __restrict__ adst4,
                          const float* __restrict__ lin_w,
                          const float* __restrict__ lin_b,
                          float* __restrict__ out_f32,
                          unsigned short* __restrict__ out_pack,
                          float* __restrict__ out_final, int N) {
    int w = threadIdx.x >> 6;
    int lane = threadIdx.x & 63;
    int quad = lane >> 4, col = lane & 15;
    int nbase = blockIdx.x * 64 + w * 16;

    f32x4 zero4 = {0.f, 0.f, 0.f, 0.f};
    f32x4 acc[4];
#pragma unroll
    for (int t = 0; t < 4; ++t) acc[t] = zero4;

    const unsigned short* arow = zb + (size_t)(nbase + col) * HC + quad * 8;
#pragma unroll
    for (int q = 0; q < 8; ++q) {
        bf16x8 af = *(const bf16x8*)(arow + q * 32);
#pragma unroll
        for (int t = 0; t < 4; ++t) {
            const unsigned short* bp = Wb + (size_t)(t * 16 + col) * HC + q * 32 + quad * 8;
            bf16x8 bfrag = *(const bf16x8*)bp;
            acc[t] = __builtin_amdgcn_mfma_f32_16x16x32_bf16(af, bfrag, acc[t], 0, 0, 0);
        }
    }

    if (!out_final) {
        float vv[4][4];   // [t][r]
#pragma unroll
        for (int t = 0; t < 4; ++t) {
            int c = t * 16 + col;
            float bc = bias[c];
#pragma unroll
            for (int r = 0; r < 4; ++r) {
                int n = nbase + quad * 4 + r;
                float v = acc[t][r] + bc;
                v = v > 0.f ? v : expm1f(v);
                v += residual[(size_t)n * CH + c];
                vv[t][r] = v;
                if (n < N) {
                    out_f32[(size_t)n * CH + c] = v;
                    out_pack[(size_t)n * CH + c] = (unsigned short)f2bf(v);
                }
            }
        }
        float4 wsv[4], wdv[4];
#pragma unroll
        for (int t = 0; t < 4; ++t) { wsv[t] = wsn4[t * 16 + col]; wdv[t] = wdn4[t * 16 + col]; }
#pragma unroll
        for (int r = 0; r < 4; ++r) {
            int n = nbase + quad * 4 + r;
            float4 sa = make_float4(0.f, 0.f, 0.f, 0.f);
            float4 da = make_float4(0.f, 0.f, 0.f, 0.f);
#pragma unroll
            for (int t = 0; t < 4; ++t) {
                float v = vv[t][r];
                sa.x += v * wsv[t].x; sa.y += v * wsv[t].y;
                sa.z += v * wsv[t].z; sa.w += v * wsv[t].w;
                da.x += v * wdv[t].x; da.y += v * wdv[t].y;
                da.z += v * wdv[t].z; da.w += v * wdv[t].w;
            }
#pragma unroll
            for (int m = 8; m; m >>= 1) {
                sa.x += __shfl_xor(sa.x, m); sa.y += __shfl_xor(sa.y, m);
                sa.z += __shfl_xor(sa.z, m); sa.w += __shfl_xor(sa.w, m);
                da.x += __shfl_xor(da.x, m); da.y += __shfl_xor(da.y, m);
                da.z += __shfl_xor(da.z, m); da.w += __shfl_xor(da.w, m);
            }
            if (col == 0 && n < N) { asrc4[n] = sa; adst4[n] = da; }
        }
    } else {
        float lw[4], bb[4];
#pragma unroll
        for (int t = 0; t < 4; ++t) { lw[t] = lin_w[t * 16 + col]; bb[t] = bias[t * 16 + col]; }
#pragma unroll
        for (int r = 0; r < 4; ++r) {
            int n = nbase + quad * 4 + r;
            float ts = 0.f;
#pragma unroll
            for (int t = 0; t < 4; ++t) {
                float v = acc[t][r] + bb[t];
                v = v > 0.f ? v : expm1f(v);
                v += residual[(size_t)n * CH + (t * 16 + col)];
                ts += v * lw[t];
            }
            ts += __shfl_xor(ts, 1);
            ts += __shfl_xor(ts, 2);
            ts += __shfl_xor(ts, 4);
            ts += __shfl_xor(ts, 8);
            if (col == 0 && n < N) out_final[n] = ts + lin_b[0];
        }
    }
}

// ---------------------------------------------------------------------------
// Layer-1 aggregation: 4 LANES per node (3125 waves; float4 x loads; logits
// inline — x[s] already loaded for the z-accumulation).
__global__ void fused1_kernel(const int* __restrict__ off,
                              const int* __restrict__ csr_src,
                              const float4* __restrict__ xq,
                              const float* __restrict__ ws,   // ws1[12], k*4+h
                              const float* __restrict__ wd,   // wd1[12]
                              float4* __restrict__ zl, int N) {
    int t = blockIdx.x * blockDim.x + threadIdx.x;
    int n = t >> 2, j = t & 3;
    if (n >= N) return;
    float4 xn = xq[n];
    float ad0 = xn.x * wd[0] + xn.y * wd[4] + xn.z * wd[8];
    float ad1 = xn.x * wd[1] + xn.y * wd[5] + xn.z * wd[9];
    float ad2 = xn.x * wd[2] + xn.y * wd[6] + xn.z * wd[10];
    float ad3 = xn.x * wd[3] + xn.y * wd[7] + xn.z * wd[11];

    int o0 = off[n], o1 = off[n + 1];
    float z[12];
#pragma unroll
    for (int q = 0; q < 12; ++q) z[q] = 0.f;
    float l0 = 0.f, l1 = 0.f, l2 = 0.f, l3 = 0.f;

    for (int i = o0 + j; i < o1; i += 4) {
        int s = csr_src[i];
        float4 xv = xq[s];
        float e0 = __expf(lrelu(xv.x * ws[0] + xv.y * ws[4] + xv.z * ws[8]  + ad0));
        float e1 = __expf(lrelu(xv.x * ws[1] + xv.y * ws[5] + xv.z * ws[9]  + ad1));
        float e2 = __expf(lrelu(xv.x * ws[2] + xv.y * ws[6] + xv.z * ws[10] + ad2));
        float e3 = __expf(lrelu(xv.x * ws[3] + xv.y * ws[7] + xv.z * ws[11] + ad3));
        l0 += e0; l1 += e1; l2 += e2; l3 += e3;
        z[0] += e0 * xv.x; z[1]  += e0 * xv.y; z[2]  += e0 * xv.z;
        z[3] += e1 * xv.x; z[4]  += e1 * xv.y; z[5]  += e1 * xv.z;
        z[6] += e2 * xv.x; z[7]  += e2 * xv.y; z[8]  += e2 * xv.z;
        z[9] += e3 * xv.x; z[10] += e3 * xv.y; z[11] += e3 * xv.z;
    }
    // reduce across the 4 lanes of this node
#pragma unroll
    for (int m = 1; m < 4; m <<= 1) {
#pragma unroll
        for (int q = 0; q < 12; ++q) z[q] += __shfl_xor(z[q], m);
        l0 += __shfl_xor(l0, m);
        l1 += __shfl_xor(l1, m);
        l2 += __shfl_xor(l2, m);
        l3 += __shfl_xor(l3, m);
    }
    if (j == 0) {
        zl[(size_t)n * 4 + 0] = make_float4(z[0], z[1], z[2], z[3]);
        zl[(size_t)n * 4 + 1] = make_float4(z[4], z[5], z[6], z[7]);
        zl[(size_t)n * 4 + 2] = make_float4(z[8], z[9], z[10], z[11]);
        zl[(size_t)n * 4 + 3] = make_float4(l0, l1, l2, l3);
    }
}

// Layer-1 epilogue: fp32 out + packed bf16 rows + FOLDED layer-2 logits.
__global__ void epi1_kernel(const float4* __restrict__ zl,
                            const float* __restrict__ W1,
                            const float* __restrict__ b1,
                            const float4* __restrict__ ws2_4,
                            const float4* __restrict__ wd2_4,
                            float4* __restrict__ asrc4,
                            float4* __restrict__ adst4,
                            float* __restrict__ out,
                            unsigned short* __restrict__ out_pack, int N) {
    int node = (blockIdx.x * blockDim.x + threadIdx.x) >> 6;
    int c = threadIdx.x & 63;
    if (node >= N) return;
    float4 z0 = zl[(size_t)node * 4 + 0];
    float4 z1 = zl[(size_t)node * 4 + 1];
    float4 z2 = zl[(size_t)node * 4 + 2];
    float4 l4 = zl[(size_t)node * 4 + 3];
    float i0 = 0.25f / l4.x, i1 = 0.25f / l4.y;
    float i2 = 0.25f / l4.z, i3 = 0.25f / l4.w;
    float acc =
        (z0.x * W1[0 * HC +   0 + c] + z0.y * W1[1 * HC +   0 + c] + z0.z * W1[2 * HC +   0 + c]) * i0 +
        (z0.w * W1[0 * HC +  64 + c] + z1.x * W1[1 * HC +  64 + c] + z1.y * W1[2 * HC +  64 + c]) * i1 +
        (z1.z * W1[0 * HC + 128 + c] + z1.w * W1[1 * HC + 128 + c] + z2.x * W1[2 * HC + 128 + c]) * i2 +
        (z2.y * W1[0 * HC + 192 + c] + z2.z * W1[1 * HC + 192 + c] + z2.w * W1[2 * HC + 192 + c]) * i3;
    float v = acc + b1[c];
    v = v > 0.f ? v : expm1f(v);
    out[(size_t)node * CH + c] = v;
    out_pack[(size_t)node * CH + c] = (unsigned short)f2bf(v);
    float4 wsv = ws2_4[c], wdv = wd2_4[c];
    float4 sacc = make_float4(v * wsv.x, v * wsv.y, v * wsv.z, v * wsv.w);
    float4 dacc = make_float4(v * wdv.x, v * wdv.y, v * wdv.z, v * wdv.w);
    sacc = wave_sum4(sacc);
    dacc = wave_sum4(dacc);
    if (c == 0) { asrc4[node] = sacc; adst4[node] = dacc; }
}

// ---------------------------------------------------------------------------
extern "C" void kernel_launch(void* const* d_in, const int* in_sizes, int n_in,
                              void* d_out, int out_size, void* d_ws, size_t ws_size,
                              hipStream_t stream) {
    const float* x      = (const float*)d_in[0];
    const int*   ei     = (const int*)  d_in[1];
    const float* W1     = (const float*)d_in[2];
    const float* a1s    = (const float*)d_in[3];
    const float* a1d    = (const float*)d_in[4];
    const float* b1     = (const float*)d_in[5];
    const float* W2     = (const float*)d_in[6];
    const float* a2s    = (const float*)d_in[7];
    const float* a2d    = (const float*)d_in[8];
    const float* b2     = (const float*)d_in[9];
    const float* W3     = (const float*)d_in[10];
    const float* a3s    = (const float*)d_in[11];
    const float* a3d    = (const float*)d_in[12];
    const float* b3     = (const float*)d_in[13];
    const float* lin_w  = (const float*)d_in[14];
    const float* lin_b  = (const float*)d_in[15];

    const int N = in_sizes[0] / 3;
    const int E = in_sizes[1] / 2;
    const int Et = E + N;
    const int* src = ei;
    const int* dst = ei + E;
    const float scale8 = 8.0f / (float)N;
    const int vec_ok = ((((size_t)src | (size_t)dst) & 15) == 0) ? 1 : 0;

    // ---- workspace layout (xq first for 16B alignment) ----
    float* xq_f   = (float*)d_ws;                         // N*4 (float4)
    unsigned short* zb  = (unsigned short*)(xq_f + (size_t)N * 4);  // N*256
    unsigned short* xpA = zb  + (size_t)N * HC;           // N*64
    unsigned short* xpB = xpA + (size_t)N * CH;           // N*64
    unsigned short* Wb2 = xpB + (size_t)N * CH;           // 16384
    unsigned short* Wb3 = Wb2 + 16384;                    // 16384
    float* bufA   = (float*)(Wb3 + 16384);                // N*64
    float* bufB   = bufA + (size_t)N * CH;                // N*64
    float* zl     = bufB + (size_t)N * CH;                // N*16
    float* asrc   = zl   + (size_t)N * 16;                // N*4
    float* adst   = asrc + (size_t)N * 4;                 // N*4
    float* ws1    = adst + (size_t)N * 4;                 // 16
    float* wd1    = ws1 + 16;                             // 16
    float* ws2    = wd1 + 16;                             // 256
    float* wd2    = ws2 + 256;                            // 256
    float* ws3    = wd2 + 256;                            // 256
    float* wd3    = ws3 + 256;                            // 256
    int* deg      = (int*)(wd3 + 256);                    // N
    int* cursor   = deg + N;                              // N (adjacent: 1 memset)
    int* off      = cursor + N;                           // N+4
    int* bsum     = off + N + 4;                          // 256
    int* csr_src  = bsum + 256;                           // Et

    const int B = 256;
    const int G = (N + 255) / 256;
    const int EB4 = (E + 3) / 4;                 // 4 edges per thread
    const int CB = (EB4 + B - 1) / B;

    // ---- CSR build ----
    hipMemsetAsync(deg, 0, (size_t)2 * N * sizeof(int), stream);  // deg+cursor
    count_kernel<<<CB * 8, B, 0, stream>>>(dst, E, vec_ok, scale8, deg);
    scan_blocks<<<G, B, 0, stream>>>(deg, off, bsum, x, (float4*)xq_f, N);
    scan_bsums<<<1, B, 0, stream>>>(bsum, G, off + N);
    scan_add<<<G, B, 0, stream>>>(off, bsum, deg, csr_src, N);
    scatter_kernel<<<CB * 8, B, 0, stream>>>(src, dst, E, vec_ok, scale8,
                                             off, cursor, csr_src);

    // ---- all weight prep in one launch ----
    prep_all<<<133, B, 0, stream>>>(W1, a1s, a1d, ws1, wd1,
                                    W2, a2s, a2d, Wb2, ws2, wd2,
                                    W3, a3s, a3d, Wb3, ws3, wd3);

    int nwave_blocks = (N * 64 + B - 1) / B;   // wave per node
    int ngemm_blocks = (N + 63) / 64;          // 64 nodes per block

    // ---- Layer 1 ----
    fused1_kernel<<<(N * 4 + B - 1) / B, B, 0, stream>>>(
        off, csr_src, (const float4*)xq_f, ws1, wd1, (float4*)zl, N);
    epi1_kernel<<<nwave_blocks, B, 0, stream>>>(
        (const float4*)zl, W1, b1, (const float4*)ws2, (const float4*)wd2,
        (float4*)asrc, (float4*)adst, bufA, xpA, N);

    // ---- Layer 2 (gemm epilogue folds layer-3 logits) ----
    agg_kernel<<<nwave_blocks, B, 0, stream>>>(
        off, csr_src, xpA, (const float4*)asrc, (const float4*)adst,
        (uint2*)zb, N);
    gemm_mfma<<<ngemm_blocks, B, 0, stream>>>(
        zb, Wb2, b2, bufA, (const float4*)ws3, (const float4*)wd3,
        (float4*)asrc, (float4*)adst,
        nullptr, nullptr, bufB, xpB, nullptr, N);

    // ---- Layer 3 (+ fused final linear) ----
    agg_kernel<<<nwave_blocks, B, 0, stream>>>(
        off, csr_src, xpB, (const float4*)asrc, (const float4*)adst,
        (uint2*)zb, N);
    gemm_mfma<<<ngemm_blocks, B, 0, stream>>>(
        zb, Wb3, b3, bufB, nullptr, nullptr, nullptr, nullptr,
        lin_w, lin_b, nullptr, nullptr, (float*)d_out, N);
}

// Round 7
// 335.072 us; speedup vs baseline: 1.0499x; 1.0281x over previous
//
#include <hip/hip_runtime.h>
#include <math.h>

#define HEADS 4
#define CH 64
#define HC 256   // HEADS*CH

typedef __attribute__((ext_vector_type(8))) short bf16x8;
typedef __attribute__((ext_vector_type(4))) float f32x4;

__device__ __forceinline__ float lrelu(float v) { return v > 0.f ? v : 0.2f * v; }

// fp32 -> bf16 bits, round-to-nearest-even
__device__ __forceinline__ unsigned int f2bf(float f) {
    unsigned int u = __float_as_uint(f);
    u += 0x7fffu + ((u >> 16) & 1u);
    return u >> 16;
}
__device__ __forceinline__ float bf2f(unsigned short u) {
    return __uint_as_float(((unsigned int)u) << 16);
}

__device__ __forceinline__ float4 wave_sum4(float4 v) {
#pragma unroll
    for (int m = 32; m; m >>= 1) {
        v.x += __shfl_xor(v.x, m);
        v.y += __shfl_xor(v.y, m);
        v.z += __shfl_xor(v.z, m);
        v.w += __shfl_xor(v.w, m);
    }
    return v;
}

// ---------------------------------------------------------------------------
// CSR build. count is XCD-affine (measured best) and RECORDS each edge's slot
// (atomicAdd return) so scatter needs NO atomics and NO 8x replication.
__global__ void count_kernel(const int* __restrict__ dst, int E, int vec_ok,
                             float scale8, int* __restrict__ deg,
                             int* __restrict__ slot) {
    int r = blockIdx.x & 7;
    int i = (blockIdx.x >> 3) * blockDim.x + threadIdx.x;
    int e0 = i * 4;
    if (e0 >= E) return;
    int d[4];
    int cnt;
    if (vec_ok && e0 + 3 < E) {
        int4 v = *(const int4*)(dst + e0);
        d[0] = v.x; d[1] = v.y; d[2] = v.z; d[3] = v.w; cnt = 4;
    } else {
        cnt = min(4, E - e0);
        for (int k = 0; k < cnt; ++k) d[k] = dst[e0 + k];
    }
    for (int k = 0; k < cnt; ++k) {
        int rr = min(7, (int)((float)d[k] * scale8));
        if (rr == r) slot[e0 + k] = atomicAdd(&deg[d[k]], 1);
    }
}

// scan pass 1 (+ float4-pack x: this grid is exactly N threads).
// Prefixes deg[g]+1 — the +1 is the implicit self-loop.
__global__ void scan_blocks(const int* __restrict__ deg,
                            int* __restrict__ off,
                            int* __restrict__ bsum,
                            const float* __restrict__ x,
                            float4* __restrict__ xq, int N) {
    __shared__ int sh[256];
    int t = threadIdx.x;
    int g = blockIdx.x * 256 + t;
    int v = (g < N) ? deg[g] + 1 : 0;
    if (g < N) xq[g] = make_float4(x[3 * g], x[3 * g + 1], x[3 * g + 2], 0.f);
    sh[t] = v;
    __syncthreads();
    for (int d = 1; d < 256; d <<= 1) {
        int xv = (t >= d) ? sh[t - d] : 0;
        __syncthreads();
        sh[t] += xv;
        __syncthreads();
    }
    if (g < N) off[g] = sh[t] - v;
    if (t == 255) bsum[blockIdx.x] = sh[255];
}

__global__ void scan_bsums(int* __restrict__ bsum, int G,
                           int* __restrict__ total_out) {
    __shared__ int sh[256];
    int t = threadIdx.x;
    int chunk = (G + 255) / 256;
    int lo = t * chunk, hi = min(lo + chunk, G);
    int s = 0;
    for (int i = lo; i < hi; ++i) s += bsum[i];
    sh[t] = s;
    __syncthreads();
    for (int d = 1; d < 256; d <<= 1) {
        int xv = (t >= d) ? sh[t - d] : 0;
        __syncthreads();
        sh[t] += xv;
        __syncthreads();
    }
    int run = (t > 0) ? sh[t - 1] : 0;
    for (int i = lo; i < hi; ++i) { int v = bsum[i]; bsum[i] = run; run += v; }
    if (t == 255) *total_out = sh[255];
}

// scan pass 3 + plain-store self-loop into the node's LAST slot.
__global__ void scan_add(int* __restrict__ off, const int* __restrict__ bsum,
                         const int* __restrict__ deg,
                         int* __restrict__ csr_src, int N) {
    int g = blockIdx.x * 256 + threadIdx.x;
    if (g < N) {
        int o = off[g] + bsum[blockIdx.x];
        off[g] = o;
        csr_src[o + deg[g]] = g;
    }
}

// Atomic-free scatter: slot was recorded by count.
__global__ void scatter_plain(const int* __restrict__ src,
                              const int* __restrict__ dst,
                              const int* __restrict__ slot, int E, int vec_ok,
                              const int* __restrict__ off,
                              int* __restrict__ csr_src) {
    int i = blockIdx.x * blockDim.x + threadIdx.x;
    int e0 = i * 4;
    if (e0 >= E) return;
    if (vec_ok && e0 + 3 < E) {
        int4 sv = *(const int4*)(src + e0);
        int4 dv = *(const int4*)(dst + e0);
        int4 pv = *(const int4*)(slot + e0);
        csr_src[off[dv.x] + pv.x] = sv.x;
        csr_src[off[dv.y] + pv.y] = sv.y;
        csr_src[off[dv.z] + pv.z] = sv.z;
        csr_src[off[dv.w] + pv.w] = sv.w;
    } else {
        int cnt = min(4, E - e0);
        for (int k = 0; k < cnt; ++k) {
            int e = e0 + k;
            csr_src[off[dst[e]] + slot[e]] = src[e];
        }
    }
}

// ---------------------------------------------------------------------------
// ALL weight prep in one launch.
__device__ __forceinline__ void prep_blk(int b, int t, const float* W,
                                         const float* a_s, const float* a_d,
                                         unsigned short* Wb, float* ws,
                                         float* wd) {
    if (b < 64) {
        Wb[b * 256 + t] = (unsigned short)f2bf(W[(t >> 2) * HC + (t & 3) * CH + b]);
    } else {
        int idx = (b - 64) * 256 + t;      // 0..511
        int which = idx >= 256;
        int i = which ? idx - 256 : idx;   // i = k*4+h
        int k = i >> 2, h = i & 3;
        const float* av = (which ? a_d : a_s) + h * CH;
        const float* Wr = W + (size_t)k * HC + h * CH;
        float s = 0.f;
        for (int c = 0; c < CH; ++c) s += Wr[c] * av[c];
        (which ? wd : ws)[i] = s;
    }
}

__global__ void prep_all(const float* __restrict__ W1,
                         const float* __restrict__ a1s,
                         const float* __restrict__ a1d,
                         float* __restrict__ ws1, float* __restrict__ wd1,
                         const float* __restrict__ W2,
                         const float* __restrict__ a2s,
                         const float* __restrict__ a2d,
                         unsigned short* __restrict__ Wb2,
                         float* __restrict__ ws2, float* __restrict__ wd2,
                         const float* __restrict__ W3,
                         const float* __restrict__ a3s,
                         const float* __restrict__ a3d,
                         unsigned short* __restrict__ Wb3,
                         float* __restrict__ ws3, float* __restrict__ wd3) {
    int b = blockIdx.x, t = threadIdx.x;
    if (b < 66) {
        prep_blk(b, t, W2, a2s, a2d, Wb2, ws2, wd2);
    } else if (b < 132) {
        prep_blk(b - 66, t, W3, a3s, a3d, Wb3, ws3, wd3);
    } else {
        for (int idx = t; idx < 24; idx += blockDim.x) {
            int which = idx >= 12;
            int i = which ? idx - 12 : idx;
            int k = i >> 2, h = i & 3;
            const float* av = (which ? a1d : a1s) + h * CH;
            const float* Wr = W1 + (size_t)k * HC + h * CH;
            float s = 0.f;
            for (int c = 0; c < CH; ++c) s += Wr[c] * av[c];
            (which ? wd1 : ws1)[i] = s;
        }
    }
}

// ---------------------------------------------------------------------------
// Input-space aggregation (layers 2/3): wave per dst node.
// Phase 2 processes TWO edges per iteration: half-wave per edge, each lane
// owns 2 k-columns (one dword = 2 bf16 per load).  Cross-half combine is a
// single shfl_xor(32) pass at the end.
__global__ void agg_kernel(const int* __restrict__ off,
                           const int* __restrict__ csr_src,
                           const unsigned short* __restrict__ xp,
                           const float4* __restrict__ asrc4,
                           const float4* __restrict__ adst4,
                           unsigned short* __restrict__ zb, int N) {
    __shared__ float4 exs[4][64];
    __shared__ unsigned int sss[4][64];
    int node = (blockIdx.x * blockDim.x + threadIdx.x) >> 6;
    int w = (threadIdx.x >> 6) & 3;
    int lane = threadIdx.x & 63;
    if (node >= N) return;
    int half = lane >> 5;          // which edge of the pair
    int lk = lane & 31;            // k-pair index: k = 2*lk, 2*lk+1
    int o0 = off[node], o1 = off[node + 1];
    int deg = o1 - o0;
    float4 ad = adst4[node];

    float l0 = 0.f, l1 = 0.f, l2 = 0.f, l3 = 0.f;
    float z[8];
#pragma unroll
    for (int q = 0; q < 8; ++q) z[q] = 0.f;
    const char* xpb2 = (const char*)xp + lk * 4;

    for (int base = 0; base < deg; base += 64) {
        int i = base + lane;
        int s = 0;
        float4 ev = make_float4(-INFINITY, -INFINITY, -INFINITY, -INFINITY);
        if (i < deg) {
            s = csr_src[o0 + i];
            float4 as = asrc4[s];
            ev.x = lrelu(as.x + ad.x);
            ev.y = lrelu(as.y + ad.y);
            ev.z = lrelu(as.z + ad.z);
            ev.w = lrelu(as.w + ad.w);
        }
        float4 ex;
        ex.x = __expf(ev.x);   // inactive lanes: exp(-inf) = 0
        ex.y = __expf(ev.y);
        ex.z = __expf(ev.z);
        ex.w = __expf(ev.w);
        float4 ls = wave_sum4(ex);
        l0 += ls.x; l1 += ls.y; l2 += ls.z; l3 += ls.w;
        exs[w][lane] = ex;
        sss[w][lane] = (unsigned)s * 128u;   // byte offset of row s in xp

        int cnt = min(64, deg - base);
        // 2 edges per iteration; inactive (odd tail) edge has ex==0.
#pragma unroll 2
        for (int e2 = 0; e2 < cnt; e2 += 2) {
            int e = e2 + half;
            unsigned soff = sss[w][e];       // 2-addr LDS broadcast (free)
            float4 exe = exs[w][e];
            unsigned xx = *(const unsigned*)(xpb2 + soff);
            float xk0 = bf2f((unsigned short)(xx & 0xffffu));
            float xk1 = bf2f((unsigned short)(xx >> 16));
            z[0] += exe.x * xk0; z[1] += exe.y * xk0;
            z[2] += exe.z * xk0; z[3] += exe.w * xk0;
            z[4] += exe.x * xk1; z[5] += exe.y * xk1;
            z[6] += exe.z * xk1; z[7] += exe.w * xk1;
        }
    }
    // combine even/odd edge chains across the two halves
#pragma unroll
    for (int q = 0; q < 8; ++q) z[q] += __shfl_xor(z[q], 32);

    float s0 = 0.25f / l0, s1 = 0.25f / l1, s2 = 0.25f / l2, s3 = 0.25f / l3;
    if (half == 0) {
        uint4 zo;   // zb[node][j], j=k*4+h: k0 -> j=8lk.., k1 -> j=8lk+4..
        zo.x = f2bf(z[0] * s0) | (f2bf(z[1] * s1) << 16);
        zo.y = f2bf(z[2] * s2) | (f2bf(z[3] * s3) << 16);
        zo.z = f2bf(z[4] * s0) | (f2bf(z[5] * s1) << 16);
        zo.w = f2bf(z[6] * s2) | (f2bf(z[7] * s3) << 16);
        *(uint4*)((char*)zb + (size_t)node * 512 + lk * 16) = zo;
    }
}

// ---------------------------------------------------------------------------
// MFMA post-aggregation GEMM (layers 2/3). A = zb (bf16 [n][j], j=k*4+h),
// B = Wb (bf16 [c][j]).  Layer-2 epilogue folds layer-3 logits; layer 3
// folds the final linear.
__global__ void gemm_mfma(const unsigned short* __restrict__ zb,
                          const unsigned short* __restrict__ Wb,
                          const float* __restrict__ bias,
                          const float* __restrict__ residual,
                          const float4* __restrict__ wsn4,
                          const float4* __restrict__ wdn4,
                          float4* __restrict__ asrc4,
                          float4* __restrict__ adst4,
                          const float* __restrict__ lin_w,
                          const float* __restrict__ lin_b,
                          float* __restrict__ out_f32,
                          unsigned short* __restrict__ out_pack,
                          float* __restrict__ out_final, int N) {
    int w = threadIdx.x >> 6;
    int lane = threadIdx.x & 63;
    int quad = lane >> 4, col = lane & 15;
    int nbase = blockIdx.x * 64 + w * 16;

    f32x4 zero4 = {0.f, 0.f, 0.f, 0.f};
    f32x4 acc[4];
#pragma unroll
    for (int t = 0; t < 4; ++t) acc[t] = zero4;

    const unsigned short* arow = zb + (size_t)(nbase + col) * HC + quad * 8;
#pragma unroll
    for (int q = 0; q < 8; ++q) {
        bf16x8 af = *(const bf16x8*)(arow + q * 32);
#pragma unroll
        for (int t = 0; t < 4; ++t) {
            const unsigned short* bp = Wb + (size_t)(t * 16 + col) * HC + q * 32 + quad * 8;
            bf16x8 bfrag = *(const bf16x8*)bp;
            acc[t] = __builtin_amdgcn_mfma_f32_16x16x32_bf16(af, bfrag, acc[t], 0, 0, 0);
        }
    }

    if (!out_final) {
        float vv[4][4];   // [t][r]
#pragma unroll
        for (int t = 0; t < 4; ++t) {
            int c = t * 16 + col;
            float bc = bias[c];
#pragma unroll
            for (int r = 0; r < 4; ++r) {
                int n = nbase + quad * 4 + r;
                float v = acc[t][r] + bc;
                v = v > 0.f ? v : expm1f(v);
                v += residual[(size_t)n * CH + c];
                vv[t][r] = v;
                if (n < N) {
                    out_f32[(size_t)n * CH + c] = v;
                    out_pack[(size_t)n * CH + c] = (unsigned short)f2bf(v);
                }
            }
        }
        float4 wsv[4], wdv[4];
#pragma unroll
        for (int t = 0; t < 4; ++t) { wsv[t] = wsn4[t * 16 + col]; wdv[t] = wdn4[t * 16 + col]; }
#pragma unroll
        for (int r = 0; r < 4; ++r) {
            int n = nbase + quad * 4 + r;
            float4 sa = make_float4(0.f, 0.f, 0.f, 0.f);
            float4 da = make_float4(0.f, 0.f, 0.f, 0.f);
#pragma unroll
            for (int t = 0; t < 4; ++t) {
                float v = vv[t][r];
                sa.x += v * wsv[t].x; sa.y += v * wsv[t].y;
                sa.z += v * wsv[t].z; sa.w += v * wsv[t].w;
                da.x += v * wdv[t].x; da.y += v * wdv[t].y;
                da.z += v * wdv[t].z; da.w += v * wdv[t].w;
            }
#pragma unroll
            for (int m = 8; m; m >>= 1) {
                sa.x += __shfl_xor(sa.x, m); sa.y += __shfl_xor(sa.y, m);
                sa.z += __shfl_xor(sa.z, m); sa.w += __shfl_xor(sa.w, m);
                da.x += __shfl_xor(da.x, m); da.y += __shfl_xor(da.y, m);
                da.z += __shfl_xor(da.z, m); da.w += __shfl_xor(da.w, m);
            }
            if (col == 0 && n < N) { asrc4[n] = sa; adst4[n] = da; }
        }
    } else {
        float lw[4], bb[4];
#pragma unroll
        for (int t = 0; t < 4; ++t) { lw[t] = lin_w[t * 16 + col]; bb[t] = bias[t * 16 + col]; }
#pragma unroll
        for (int r = 0; r < 4; ++r) {
            int n = nbase + quad * 4 + r;
            float ts = 0.f;
#pragma unroll
            for (int t = 0; t < 4; ++t) {
                float v = acc[t][r] + bb[t];
                v = v > 0.f ? v : expm1f(v);
                v += residual[(size_t)n * CH + (t * 16 + col)];
                ts += v * lw[t];
            }
            ts += __shfl_xor(ts, 1);
            ts += __shfl_xor(ts, 2);
            ts += __shfl_xor(ts, 4);
            ts += __shfl_xor(ts, 8);
            if (col == 0 && n < N) out_final[n] = ts + lin_b[0];
        }
    }
}

// ---------------------------------------------------------------------------
// Layer 1 fully in one kernel: 4 lanes per node do the edge aggregation
// (logits inline from xq), 4-lane reduce of z[12]+l[4], then EACH lane runs
// the epilogue for 16 output channels (fp32 out + bf16 pack + folded
// layer-2 logits, 4-lane reduced).  Replaces fused1+epi1 (one dispatch,
// no zl round-trip, 16-shuffle fold instead of 48).
__global__ void layer1_kernel(const int* __restrict__ off,
                              const int* __restrict__ csr_src,
                              const float4* __restrict__ xq,
                              const float* __restrict__ ws,   // ws1[12], k*4+h
                              const float* __restrict__ wd,   // wd1[12]
                              const float* __restrict__ W1,
                              const float* __restrict__ b1,
                              const float4* __restrict__ ws2_4,
                              const float4* __restrict__ wd2_4,
                              float4* __restrict__ asrc4,
                              float4* __restrict__ adst4,
                              float* __restrict__ out,
                              unsigned short* __restrict__ out_pack, int N) {
    int t = blockIdx.x * blockDim.x + threadIdx.x;
    int n = t >> 2, j = t & 3;
    if (n >= N) return;
    float4 xn = xq[n];
    float ad0 = xn.x * wd[0] + xn.y * wd[4] + xn.z * wd[8];
    float ad1 = xn.x * wd[1] + xn.y * wd[5] + xn.z * wd[9];
    float ad2 = xn.x * wd[2] + xn.y * wd[6] + xn.z * wd[10];
    float ad3 = xn.x * wd[3] + xn.y * wd[7] + xn.z * wd[11];

    int o0 = off[n], o1 = off[n + 1];
    float z[12];
#pragma unroll
    for (int q = 0; q < 12; ++q) z[q] = 0.f;
    float l0 = 0.f, l1 = 0.f, l2 = 0.f, l3 = 0.f;

    for (int i = o0 + j; i < o1; i += 4) {
        int s = csr_src[i];
        float4 xv = xq[s];
        float e0 = __expf(lrelu(xv.x * ws[0] + xv.y * ws[4] + xv.z * ws[8]  + ad0));
        float e1 = __expf(lrelu(xv.x * ws[1] + xv.y * ws[5] + xv.z * ws[9]  + ad1));
        float e2 = __expf(lrelu(xv.x * ws[2] + xv.y * ws[6] + xv.z * ws[10] + ad2));
        float e3 = __expf(lrelu(xv.x * ws[3] + xv.y * ws[7] + xv.z * ws[11] + ad3));
        l0 += e0; l1 += e1; l2 += e2; l3 += e3;
        z[0] += e0 * xv.x; z[1]  += e0 * xv.y; z[2]  += e0 * xv.z;
        z[3] += e1 * xv.x; z[4]  += e1 * xv.y; z[5]  += e1 * xv.z;
        z[6] += e2 * xv.x; z[7]  += e2 * xv.y; z[8]  += e2 * xv.z;
        z[9] += e3 * xv.x; z[10] += e3 * xv.y; z[11] += e3 * xv.z;
    }
    // reduce across the 4 lanes of this node (all lanes get full sums)
#pragma unroll
    for (int m = 1; m < 4; m <<= 1) {
#pragma unroll
        for (int q = 0; q < 12; ++q) z[q] += __shfl_xor(z[q], m);
        l0 += __shfl_xor(l0, m);
        l1 += __shfl_xor(l1, m);
        l2 += __shfl_xor(l2, m);
        l3 += __shfl_xor(l3, m);
    }
    float ih[4];
    ih[0] = 0.25f / l0; ih[1] = 0.25f / l1; ih[2] = 0.25f / l2; ih[3] = 0.25f / l3;

    // epilogue: this lane handles channels c = j*16 .. j*16+15
    float4 sacc = make_float4(0.f, 0.f, 0.f, 0.f);
    float4 dacc = make_float4(0.f, 0.f, 0.f, 0.f);
    float* orow = out + (size_t)n * CH + j * 16;
    unsigned short* prow = out_pack + (size_t)n * CH + j * 16;
#pragma unroll
    for (int g = 0; g < 4; ++g) {          // 4 channels per group
        int cbase = j * 16 + g * 4;
        float4 a = *(const float4*)(b1 + cbase);
#pragma unroll
        for (int h = 0; h < 4; ++h) {
#pragma unroll
            for (int r = 0; r < 3; ++r) {
                float4 wv = *(const float4*)(W1 + r * HC + h * 64 + cbase);
                float zz = z[h * 3 + r] * ih[h];
                a.x += zz * wv.x; a.y += zz * wv.y;
                a.z += zz * wv.z; a.w += zz * wv.w;
            }
        }
        float v0 = a.x > 0.f ? a.x : expm1f(a.x);
        float v1 = a.y > 0.f ? a.y : expm1f(a.y);
        float v2 = a.z > 0.f ? a.z : expm1f(a.z);
        float v3 = a.w > 0.f ? a.w : expm1f(a.w);
        *(float4*)(orow + g * 4) = make_float4(v0, v1, v2, v3);
        uint2 pk;
        pk.x = f2bf(v0) | (f2bf(v1) << 16);
        pk.y = f2bf(v2) | (f2bf(v3) << 16);
        *(uint2*)(prow + g * 4) = pk;
        float4 w0 = ws2_4[cbase], w1 = ws2_4[cbase + 1];
        float4 w2 = ws2_4[cbase + 2], w3 = ws2_4[cbase + 3];
        sacc.x += v0 * w0.x + v1 * w1.x + v2 * w2.x + v3 * w3.x;
        sacc.y += v0 * w0.y + v1 * w1.y + v2 * w2.y + v3 * w3.y;
        sacc.z += v0 * w0.z + v1 * w1.z + v2 * w2.z + v3 * w3.z;
        sacc.w += v0 * w0.w + v1 * w1.w + v2 * w2.w + v3 * w3.w;
        float4 d0 = wd2_4[cbase], d1 = wd2_4[cbase + 1];
        float4 d2 = wd2_4[cbase + 2], d3 = wd2_4[cbase + 3];
        dacc.x += v0 * d0.x + v1 * d1.x + v2 * d2.x + v3 * d3.x;
        dacc.y += v0 * d0.y + v1 * d1.y + v2 * d2.y + v3 * d3.y;
        dacc.z += v0 * d0.z + v1 * d1.z + v2 * d2.z + v3 * d3.z;
        dacc.w += v0 * d0.w + v1 * d1.w + v2 * d2.w + v3 * d3.w;
    }
    // fold-reduce across the 4 lanes
#pragma unroll
    for (int m = 1; m < 4; m <<= 1) {
        sacc.x += __shfl_xor(sacc.x, m); sacc.y += __shfl_xor(sacc.y, m);
        sacc.z += __shfl_xor(sacc.z, m); sacc.w += __shfl_xor(sacc.w, m);
        dacc.x += __shfl_xor(dacc.x, m); dacc.y += __shfl_xor(dacc.y, m);
        dacc.z += __shfl_xor(dacc.z, m); dacc.w += __shfl_xor(dacc.w, m);
    }
    if (j == 0) { asrc4[n] = sacc; adst4[n] = dacc; }
}

// ---------------------------------------------------------------------------
extern "C" void kernel_launch(void* const* d_in, const int* in_sizes, int n_in,
                              void* d_out, int out_size, void* d_ws, size_t ws_size,
                              hipStream_t stream) {
    const float* x      = (const float*)d_in[0];
    const int*   ei     = (const int*)  d_in[1];
    const float* W1     = (const float*)d_in[2];
    const float* a1s    = (const float*)d_in[3];
    const float* a1d    = (const float*)d_in[4];
    const float* b1     = (const float*)d_in[5];
    const float* W2     = (const float*)d_in[6];
    const float* a2s    = (const float*)d_in[7];
    const float* a2d    = (const float*)d_in[8];
    const float* b2     = (const float*)d_in[9];
    const float* W3     = (const float*)d_in[10];
    const float* a3s    = (const float*)d_in[11];
    const float* a3d    = (const float*)d_in[12];
    const float* b3     = (const float*)d_in[13];
    const float* lin_w  = (const float*)d_in[14];
    const float* lin_b  = (const float*)d_in[15];

    const int N = in_sizes[0] / 3;
    const int E = in_sizes[1] / 2;
    const int Et = E + N;
    const int* src = ei;
    const int* dst = ei + E;
    const float scale8 = 8.0f / (float)N;
    const int vec_ok = ((((size_t)src | (size_t)dst) & 15) == 0) ? 1 : 0;

    // ---- workspace layout (xq first for 16B alignment) ----
    float* xq_f   = (float*)d_ws;                         // N*4 (float4)
    unsigned short* zb  = (unsigned short*)(xq_f + (size_t)N * 4);  // N*256
    unsigned short* xpA = zb  + (size_t)N * HC;           // N*64
    unsigned short* xpB = xpA + (size_t)N * CH;           // N*64
    unsigned short* Wb2 = xpB + (size_t)N * CH;           // 16384
    unsigned short* Wb3 = Wb2 + 16384;                    // 16384
    float* bufA   = (float*)(Wb3 + 16384);                // N*64
    float* bufB   = bufA + (size_t)N * CH;                // N*64
    float* asrc   = bufB + (size_t)N * CH;                // N*4
    float* adst   = asrc + (size_t)N * 4;                 // N*4
    float* ws1    = adst + (size_t)N * 4;                 // 16
    float* wd1    = ws1 + 16;                             // 16
    float* ws2    = wd1 + 16;                             // 256
    float* wd2    = ws2 + 256;                            // 256
    float* ws3    = wd2 + 256;                            // 256
    float* wd3    = ws3 + 256;                            // 256
    int* deg      = (int*)(wd3 + 256);                    // N
    int* off      = deg + N;                              // N+4
    int* bsum     = off + N + 4;                          // 256
    int* slot     = bsum + 256;                           // E
    int* csr_src  = slot + E;                             // Et

    const int B = 256;
    const int G = (N + 255) / 256;
    const int EB4 = (E + 3) / 4;                 // 4 edges per thread
    const int CB = (EB4 + B - 1) / B;

    // ---- CSR build ----
    hipMemsetAsync(deg, 0, (size_t)N * sizeof(int), stream);
    count_kernel<<<CB * 8, B, 0, stream>>>(dst, E, vec_ok, scale8, deg, slot);
    scan_blocks<<<G, B, 0, stream>>>(deg, off, bsum, x, (float4*)xq_f, N);
    scan_bsums<<<1, B, 0, stream>>>(bsum, G, off + N);
    scan_add<<<G, B, 0, stream>>>(off, bsum, deg, csr_src, N);
    scatter_plain<<<CB, B, 0, stream>>>(src, dst, slot, E, vec_ok, off, csr_src);

    // ---- all weight prep in one launch ----
    prep_all<<<133, B, 0, stream>>>(W1, a1s, a1d, ws1, wd1,
                                    W2, a2s, a2d, Wb2, ws2, wd2,
                                    W3, a3s, a3d, Wb3, ws3, wd3);

    int nwave_blocks = (N * 64 + B - 1) / B;   // wave per node (agg)
    int ngemm_blocks = (N + 63) / 64;          // 64 nodes per block

    // ---- Layer 1 (single kernel: agg + epilogue + folded layer-2 logits) ----
    layer1_kernel<<<(N * 4 + B - 1) / B, B, 0, stream>>>(
        off, csr_src, (const float4*)xq_f, ws1, wd1, W1, b1,
        (const float4*)ws2, (const float4*)wd2,
        (float4*)asrc, (float4*)adst, bufA, xpA, N);

    // ---- Layer 2 (gemm epilogue folds layer-3 logits) ----
    agg_kernel<<<nwave_blocks, B, 0, stream>>>(
        off, csr_src, xpA, (const float4*)asrc, (const float4*)adst,
        zb, N);
    gemm_mfma<<<ngemm_blocks, B, 0, stream>>>(
        zb, Wb2, b2, bufA, (const float4*)ws3, (const float4*)wd3,
        (float4*)asrc, (float4*)adst,
        nullptr, nullptr, bufB, xpB, nullptr, N);

    // ---- Layer 3 (+ fused final linear) ----
    agg_kernel<<<nwave_blocks, B, 0, stream>>>(
        off, csr_src, xpB, (const float4*)asrc, (const float4*)adst,
        zb, N);
    gemm_mfma<<<ngemm_blocks, B, 0, stream>>>(
        zb, Wb3, b3, bufB, nullptr, nullptr, nullptr, nullptr,
        lin_w, lin_b, nullptr, nullptr, (float*)d_out, N);
}

// Round 8
// 319.785 us; speedup vs baseline: 1.1000x; 1.0478x over previous
//
#include <hip/hip_runtime.h>
#include <math.h>

#define HEADS 4
#define CH 64
#define HC 256   // HEADS*CH

typedef __attribute__((ext_vector_type(8))) short bf16x8;
typedef __attribute__((ext_vector_type(4))) float f32x4;

__device__ __forceinline__ float lrelu(float v) { return v > 0.f ? v : 0.2f * v; }

// fp32 -> bf16 bits, round-to-nearest-even
__device__ __forceinline__ unsigned int f2bf(float f) {
    unsigned int u = __float_as_uint(f);
    u += 0x7fffu + ((u >> 16) & 1u);
    return u >> 16;
}
__device__ __forceinline__ float bf2f(unsigned short u) {
    return __uint_as_float(((unsigned int)u) << 16);
}

__device__ __forceinline__ float4 wave_sum4(float4 v) {
#pragma unroll
    for (int m = 32; m; m >>= 1) {
        v.x += __shfl_xor(v.x, m);
        v.y += __shfl_xor(v.y, m);
        v.z += __shfl_xor(v.z, m);
        v.w += __shfl_xor(v.w, m);
    }
    return v;
}

// ---------------------------------------------------------------------------
// CSR build. count is XCD-affine (measured best) and RECORDS each edge's slot
// (atomicAdd return) so scatter needs NO atomics and NO 8x replication.
__global__ void count_kernel(const int* __restrict__ dst, int E, int vec_ok,
                             float scale8, int* __restrict__ deg,
                             int* __restrict__ slot) {
    int r = blockIdx.x & 7;
    int i = (blockIdx.x >> 3) * blockDim.x + threadIdx.x;
    int e0 = i * 4;
    if (e0 >= E) return;
    int d[4];
    int cnt;
    if (vec_ok && e0 + 3 < E) {
        int4 v = *(const int4*)(dst + e0);
        d[0] = v.x; d[1] = v.y; d[2] = v.z; d[3] = v.w; cnt = 4;
    } else {
        cnt = min(4, E - e0);
        for (int k = 0; k < cnt; ++k) d[k] = dst[e0 + k];
    }
    for (int k = 0; k < cnt; ++k) {
        int rr = min(7, (int)((float)d[k] * scale8));
        if (rr == r) slot[e0 + k] = atomicAdd(&deg[d[k]], 1);
    }
}

// scan pass 1 (+ float4-pack x: this grid is exactly N threads).
// Prefixes deg[g]+1 — the +1 is the implicit self-loop.
__global__ void scan_blocks(const int* __restrict__ deg,
                            int* __restrict__ off,
                            int* __restrict__ bsum,
                            const float* __restrict__ x,
                            float4* __restrict__ xq, int N) {
    __shared__ int sh[256];
    int t = threadIdx.x;
    int g = blockIdx.x * 256 + t;
    int v = (g < N) ? deg[g] + 1 : 0;
    if (g < N) xq[g] = make_float4(x[3 * g], x[3 * g + 1], x[3 * g + 2], 0.f);
    sh[t] = v;
    __syncthreads();
    for (int d = 1; d < 256; d <<= 1) {
        int xv = (t >= d) ? sh[t - d] : 0;
        __syncthreads();
        sh[t] += xv;
        __syncthreads();
    }
    if (g < N) off[g] = sh[t] - v;
    if (t == 255) bsum[blockIdx.x] = sh[255];
}

__global__ void scan_bsums(int* __restrict__ bsum, int G,
                           int* __restrict__ total_out) {
    __shared__ int sh[256];
    int t = threadIdx.x;
    int chunk = (G + 255) / 256;
    int lo = t * chunk, hi = min(lo + chunk, G);
    int s = 0;
    for (int i = lo; i < hi; ++i) s += bsum[i];
    sh[t] = s;
    __syncthreads();
    for (int d = 1; d < 256; d <<= 1) {
        int xv = (t >= d) ? sh[t - d] : 0;
        __syncthreads();
        sh[t] += xv;
        __syncthreads();
    }
    int run = (t > 0) ? sh[t - 1] : 0;
    for (int i = lo; i < hi; ++i) { int v = bsum[i]; bsum[i] = run; run += v; }
    if (t == 255) *total_out = sh[255];
}

// scan pass 3 + plain-store self-loop into the node's LAST slot.
__global__ void scan_add(int* __restrict__ off, const int* __restrict__ bsum,
                         const int* __restrict__ deg,
                         int* __restrict__ csr_src, int N) {
    int g = blockIdx.x * 256 + threadIdx.x;
    if (g < N) {
        int o = off[g] + bsum[blockIdx.x];
        off[g] = o;
        csr_src[o + deg[g]] = g;
    }
}

// Atomic-free scatter: slot was recorded by count.
__global__ void scatter_plain(const int* __restrict__ src,
                              const int* __restrict__ dst,
                              const int* __restrict__ slot, int E, int vec_ok,
                              const int* __restrict__ off,
                              int* __restrict__ csr_src) {
    int i = blockIdx.x * blockDim.x + threadIdx.x;
    int e0 = i * 4;
    if (e0 >= E) return;
    if (vec_ok && e0 + 3 < E) {
        int4 sv = *(const int4*)(src + e0);
        int4 dv = *(const int4*)(dst + e0);
        int4 pv = *(const int4*)(slot + e0);
        csr_src[off[dv.x] + pv.x] = sv.x;
        csr_src[off[dv.y] + pv.y] = sv.y;
        csr_src[off[dv.z] + pv.z] = sv.z;
        csr_src[off[dv.w] + pv.w] = sv.w;
    } else {
        int cnt = min(4, E - e0);
        for (int k = 0; k < cnt; ++k) {
            int e = e0 + k;
            csr_src[off[dst[e]] + slot[e]] = src[e];
        }
    }
}

// ---------------------------------------------------------------------------
// ALL weight prep in one launch.
__device__ __forceinline__ void prep_blk(int b, int t, const float* W,
                                         const float* a_s, const float* a_d,
                                         unsigned short* Wb, float* ws,
                                         float* wd) {
    if (b < 64) {
        Wb[b * 256 + t] = (unsigned short)f2bf(W[(t >> 2) * HC + (t & 3) * CH + b]);
    } else {
        int idx = (b - 64) * 256 + t;      // 0..511
        int which = idx >= 256;
        int i = which ? idx - 256 : idx;   // i = k*4+h
        int k = i >> 2, h = i & 3;
        const float* av = (which ? a_d : a_s) + h * CH;
        const float* Wr = W + (size_t)k * HC + h * CH;
        float s = 0.f;
        for (int c = 0; c < CH; ++c) s += Wr[c] * av[c];
        (which ? wd : ws)[i] = s;
    }
}

__global__ void prep_all(const float* __restrict__ W1,
                         const float* __restrict__ a1s,
                         const float* __restrict__ a1d,
                         float* __restrict__ ws1, float* __restrict__ wd1,
                         const float* __restrict__ W2,
                         const float* __restrict__ a2s,
                         const float* __restrict__ a2d,
                         unsigned short* __restrict__ Wb2,
                         float* __restrict__ ws2, float* __restrict__ wd2,
                         const float* __restrict__ W3,
                         const float* __restrict__ a3s,
                         const float* __restrict__ a3d,
                         unsigned short* __restrict__ Wb3,
                         float* __restrict__ ws3, float* __restrict__ wd3) {
    int b = blockIdx.x, t = threadIdx.x;
    if (b < 66) {
        prep_blk(b, t, W2, a2s, a2d, Wb2, ws2, wd2);
    } else if (b < 132) {
        prep_blk(b - 66, t, W3, a3s, a3d, Wb3, ws3, wd3);
    } else {
        for (int idx = t; idx < 24; idx += blockDim.x) {
            int which = idx >= 12;
            int i = which ? idx - 12 : idx;
            int k = i >> 2, h = i & 3;
            const float* av = (which ? a1d : a1s) + h * CH;
            const float* Wr = W1 + (size_t)k * HC + h * CH;
            float s = 0.f;
            for (int c = 0; c < CH; ++c) s += Wr[c] * av[c];
            (which ? wd1 : ws1)[i] = s;
        }
    }
}

// ---------------------------------------------------------------------------
// Input-space aggregation (layers 2/3): wave per dst node.
// Phase 2 processes TWO edges per iteration: half-wave per edge, each lane
// owns 2 k-columns (one dword = 2 bf16 per load).  Cross-half combine is a
// single shfl_xor(32) pass at the end.
__global__ void agg_kernel(const int* __restrict__ off,
                           const int* __restrict__ csr_src,
                           const unsigned short* __restrict__ xp,
                           const float4* __restrict__ asrc4,
                           const float4* __restrict__ adst4,
                           unsigned short* __restrict__ zb, int N) {
    __shared__ float4 exs[4][64];
    __shared__ unsigned int sss[4][64];
    int node = (blockIdx.x * blockDim.x + threadIdx.x) >> 6;
    int w = (threadIdx.x >> 6) & 3;
    int lane = threadIdx.x & 63;
    if (node >= N) return;
    int half = lane >> 5;          // which edge of the pair
    int lk = lane & 31;            // k-pair index: k = 2*lk, 2*lk+1
    int o0 = off[node], o1 = off[node + 1];
    int deg = o1 - o0;
    float4 ad = adst4[node];

    float l0 = 0.f, l1 = 0.f, l2 = 0.f, l3 = 0.f;
    float z[8];
#pragma unroll
    for (int q = 0; q < 8; ++q) z[q] = 0.f;
    const char* xpb2 = (const char*)xp + lk * 4;

    for (int base = 0; base < deg; base += 64) {
        int i = base + lane;
        int s = 0;
        float4 ev = make_float4(-INFINITY, -INFINITY, -INFINITY, -INFINITY);
        if (i < deg) {
            s = csr_src[o0 + i];
            float4 as = asrc4[s];
            ev.x = lrelu(as.x + ad.x);
            ev.y = lrelu(as.y + ad.y);
            ev.z = lrelu(as.z + ad.z);
            ev.w = lrelu(as.w + ad.w);
        }
        float4 ex;
        ex.x = __expf(ev.x);   // inactive lanes: exp(-inf) = 0
        ex.y = __expf(ev.y);
        ex.z = __expf(ev.z);
        ex.w = __expf(ev.w);
        float4 ls = wave_sum4(ex);
        l0 += ls.x; l1 += ls.y; l2 += ls.z; l3 += ls.w;
        exs[w][lane] = ex;
        sss[w][lane] = (unsigned)s * 128u;   // byte offset of row s in xp

        int cnt = min(64, deg - base);
        // 2 edges per iteration; inactive (odd tail) edge has ex==0.
#pragma unroll 2
        for (int e2 = 0; e2 < cnt; e2 += 2) {
            int e = e2 + half;
            unsigned soff = sss[w][e];       // 2-addr LDS broadcast (free)
            float4 exe = exs[w][e];
            unsigned xx = *(const unsigned*)(xpb2 + soff);
            float xk0 = bf2f((unsigned short)(xx & 0xffffu));
            float xk1 = bf2f((unsigned short)(xx >> 16));
            z[0] += exe.x * xk0; z[1] += exe.y * xk0;
            z[2] += exe.z * xk0; z[3] += exe.w * xk0;
            z[4] += exe.x * xk1; z[5] += exe.y * xk1;
            z[6] += exe.z * xk1; z[7] += exe.w * xk1;
        }
    }
    // combine even/odd edge chains across the two halves
#pragma unroll
    for (int q = 0; q < 8; ++q) z[q] += __shfl_xor(z[q], 32);

    float s0 = 0.25f / l0, s1 = 0.25f / l1, s2 = 0.25f / l2, s3 = 0.25f / l3;
    if (half == 0) {
        uint4 zo;   // zb[node][j], j=k*4+h: k0 -> j=8lk.., k1 -> j=8lk+4..
        zo.x = f2bf(z[0] * s0) | (f2bf(z[1] * s1) << 16);
        zo.y = f2bf(z[2] * s2) | (f2bf(z[3] * s3) << 16);
        zo.z = f2bf(z[4] * s0) | (f2bf(z[5] * s1) << 16);
        zo.w = f2bf(z[6] * s2) | (f2bf(z[7] * s3) << 16);
        *(uint4*)((char*)zb + (size_t)node * 512 + lk * 16) = zo;
    }
}

// ---------------------------------------------------------------------------
// MFMA post-aggregation GEMM (layers 2/3). A = zb (bf16 [n][j], j=k*4+h),
// B = Wb (bf16 [c][j]).  Layer-2 epilogue folds layer-3 logits; layer 3
// folds the final linear.
__global__ void gemm_mfma(const unsigned short* __restrict__ zb,
                          const unsigned short* __restrict__ Wb,
                          const float* __restrict__ bias,
                          const float* __restrict__ residual,
                          const float4* __restrict__ wsn4,
                          const float4* __restrict__ wdn4,
                          float4* __restrict__ asrc4,
                          float4* __restrict__ adst4,
                          const float* __restrict__ lin_w,
                          const float* __restrict__ lin_b,
                          float* __restrict__ out_f32,
                          unsigned short* __restrict__ out_pack,
                          float* __restrict__ out_final, int N) {
    int w = threadIdx.x >> 6;
    int lane = threadIdx.x & 63;
    int quad = lane >> 4, col = lane & 15;
    int nbase = blockIdx.x * 64 + w * 16;

    f32x4 zero4 = {0.f, 0.f, 0.f, 0.f};
    f32x4 acc[4];
#pragma unroll
    for (int t = 0; t < 4; ++t) acc[t] = zero4;

    const unsigned short* arow = zb + (size_t)(nbase + col) * HC + quad * 8;
#pragma unroll
    for (int q = 0; q < 8; ++q) {
        bf16x8 af = *(const bf16x8*)(arow + q * 32);
#pragma unroll
        for (int t = 0; t < 4; ++t) {
            const unsigned short* bp = Wb + (size_t)(t * 16 + col) * HC + q * 32 + quad * 8;
            bf16x8 bfrag = *(const bf16x8*)bp;
            acc[t] = __builtin_amdgcn_mfma_f32_16x16x32_bf16(af, bfrag, acc[t], 0, 0, 0);
        }
    }

    if (!out_final) {
        float vv[4][4];   // [t][r]
#pragma unroll
        for (int t = 0; t < 4; ++t) {
            int c = t * 16 + col;
            float bc = bias[c];
#pragma unroll
            for (int r = 0; r < 4; ++r) {
                int n = nbase + quad * 4 + r;
                float v = acc[t][r] + bc;
                v = v > 0.f ? v : expm1f(v);
                v += residual[(size_t)n * CH + c];
                vv[t][r] = v;
                if (n < N) {
                    out_f32[(size_t)n * CH + c] = v;
                    out_pack[(size_t)n * CH + c] = (unsigned short)f2bf(v);
                }
            }
        }
        float4 wsv[4], wdv[4];
#pragma unroll
        for (int t = 0; t < 4; ++t) { wsv[t] = wsn4[t * 16 + col]; wdv[t] = wdn4[t * 16 + col]; }
#pragma unroll
        for (int r = 0; r < 4; ++r) {
            int n = nbase + quad * 4 + r;
            float4 sa = make_float4(0.f, 0.f, 0.f, 0.f);
            float4 da = make_float4(0.f, 0.f, 0.f, 0.f);
#pragma unroll
            for (int t = 0; t < 4; ++t) {
                float v = vv[t][r];
                sa.x += v * wsv[t].x; sa.y += v * wsv[t].y;
                sa.z += v * wsv[t].z; sa.w += v * wsv[t].w;
                da.x += v * wdv[t].x; da.y += v * wdv[t].y;
                da.z += v * wdv[t].z; da.w += v * wdv[t].w;
            }
#pragma unroll
            for (int m = 8; m; m >>= 1) {
                sa.x += __shfl_xor(sa.x, m); sa.y += __shfl_xor(sa.y, m);
                sa.z += __shfl_xor(sa.z, m); sa.w += __shfl_xor(sa.w, m);
                da.x += __shfl_xor(da.x, m); da.y += __shfl_xor(da.y, m);
                da.z += __shfl_xor(da.z, m); da.w += __shfl_xor(da.w, m);
            }
            if (col == 0 && n < N) { asrc4[n] = sa; adst4[n] = da; }
        }
    } else {
        float lw[4], bb[4];
#pragma unroll
        for (int t = 0; t < 4; ++t) { lw[t] = lin_w[t * 16 + col]; bb[t] = bias[t * 16 + col]; }
#pragma unroll
        for (int r = 0; r < 4; ++r) {
            int n = nbase + quad * 4 + r;
            float ts = 0.f;
#pragma unroll
            for (int t = 0; t < 4; ++t) {
                float v = acc[t][r] + bb[t];
                v = v > 0.f ? v : expm1f(v);
                v += residual[(size_t)n * CH + (t * 16 + col)];
                ts += v * lw[t];
            }
            ts += __shfl_xor(ts, 1);
            ts += __shfl_xor(ts, 2);
            ts += __shfl_xor(ts, 4);
            ts += __shfl_xor(ts, 8);
            if (col == 0 && n < N) out_final[n] = ts + lin_b[0];
        }
    }
}

// ---------------------------------------------------------------------------
// Layer-1 aggregation: 4 LANES per node (3125 waves; float4 x loads; logits
// inline — x[s] already loaded for the z-accumulation).  Writes compact zl.
__global__ void fused1_kernel(const int* __restrict__ off,
                              const int* __restrict__ csr_src,
                              const float4* __restrict__ xq,
                              const float* __restrict__ ws,   // ws1[12], k*4+h
                              const float* __restrict__ wd,   // wd1[12]
                              float4* __restrict__ zl, int N) {
    int t = blockIdx.x * blockDim.x + threadIdx.x;
    int n = t >> 2, j = t & 3;
    if (n >= N) return;
    float4 xn = xq[n];
    float ad0 = xn.x * wd[0] + xn.y * wd[4] + xn.z * wd[8];
    float ad1 = xn.x * wd[1] + xn.y * wd[5] + xn.z * wd[9];
    float ad2 = xn.x * wd[2] + xn.y * wd[6] + xn.z * wd[10];
    float ad3 = xn.x * wd[3] + xn.y * wd[7] + xn.z * wd[11];

    int o0 = off[n], o1 = off[n + 1];
    float z[12];
#pragma unroll
    for (int q = 0; q < 12; ++q) z[q] = 0.f;
    float l0 = 0.f, l1 = 0.f, l2 = 0.f, l3 = 0.f;

    for (int i = o0 + j; i < o1; i += 4) {
        int s = csr_src[i];
        float4 xv = xq[s];
        float e0 = __expf(lrelu(xv.x * ws[0] + xv.y * ws[4] + xv.z * ws[8]  + ad0));
        float e1 = __expf(lrelu(xv.x * ws[1] + xv.y * ws[5] + xv.z * ws[9]  + ad1));
        float e2 = __expf(lrelu(xv.x * ws[2] + xv.y * ws[6] + xv.z * ws[10] + ad2));
        float e3 = __expf(lrelu(xv.x * ws[3] + xv.y * ws[7] + xv.z * ws[11] + ad3));
        l0 += e0; l1 += e1; l2 += e2; l3 += e3;
        z[0] += e0 * xv.x; z[1]  += e0 * xv.y; z[2]  += e0 * xv.z;
        z[3] += e1 * xv.x; z[4]  += e1 * xv.y; z[5]  += e1 * xv.z;
        z[6] += e2 * xv.x; z[7]  += e2 * xv.y; z[8]  += e2 * xv.z;
        z[9] += e3 * xv.x; z[10] += e3 * xv.y; z[11] += e3 * xv.z;
    }
    // reduce across the 4 lanes of this node
#pragma unroll
    for (int m = 1; m < 4; m <<= 1) {
#pragma unroll
        for (int q = 0; q < 12; ++q) z[q] += __shfl_xor(z[q], m);
        l0 += __shfl_xor(l0, m);
        l1 += __shfl_xor(l1, m);
        l2 += __shfl_xor(l2, m);
        l3 += __shfl_xor(l3, m);
    }
    if (j == 0) {
        zl[(size_t)n * 4 + 0] = make_float4(z[0], z[1], z[2], z[3]);
        zl[(size_t)n * 4 + 1] = make_float4(z[4], z[5], z[6], z[7]);
        zl[(size_t)n * 4 + 2] = make_float4(z[8], z[9], z[10], z[11]);
        zl[(size_t)n * 4 + 3] = make_float4(l0, l1, l2, l3);
    }
}

// Layer-1 epilogue: wave per node (12.5k blocks — high occupancy, coalesced
// writes).  fp32 out + packed bf16 rows + FOLDED layer-2 logits.
__global__ void epi1_kernel(const float4* __restrict__ zl,
                            const float* __restrict__ W1,
                            const float* __restrict__ b1,
                            const float4* __restrict__ ws2_4,
                            const float4* __restrict__ wd2_4,
                            float4* __restrict__ asrc4,
                            float4* __restrict__ adst4,
                            float* __restrict__ out,
                            unsigned short* __restrict__ out_pack, int N) {
    int node = (blockIdx.x * blockDim.x + threadIdx.x) >> 6;
    int c = threadIdx.x & 63;
    if (node >= N) return;
    float4 z0 = zl[(size_t)node * 4 + 0];
    float4 z1 = zl[(size_t)node * 4 + 1];
    float4 z2 = zl[(size_t)node * 4 + 2];
    float4 l4 = zl[(size_t)node * 4 + 3];
    float i0 = 0.25f / l4.x, i1 = 0.25f / l4.y;
    float i2 = 0.25f / l4.z, i3 = 0.25f / l4.w;
    float acc =
        (z0.x * W1[0 * HC +   0 + c] + z0.y * W1[1 * HC +   0 + c] + z0.z * W1[2 * HC +   0 + c]) * i0 +
        (z0.w * W1[0 * HC +  64 + c] + z1.x * W1[1 * HC +  64 + c] + z1.y * W1[2 * HC +  64 + c]) * i1 +
        (z1.z * W1[0 * HC + 128 + c] + z1.w * W1[1 * HC + 128 + c] + z2.x * W1[2 * HC + 128 + c]) * i2 +
        (z2.y * W1[0 * HC + 192 + c] + z2.z * W1[1 * HC + 192 + c] + z2.w * W1[2 * HC + 192 + c]) * i3;
    float v = acc + b1[c];
    v = v > 0.f ? v : expm1f(v);
    out[(size_t)node * CH + c] = v;
    out_pack[(size_t)node * CH + c] = (unsigned short)f2bf(v);
    float4 wsv = ws2_4[c], wdv = wd2_4[c];
    float4 sacc = make_float4(v * wsv.x, v * wsv.y, v * wsv.z, v * wsv.w);
    float4 dacc = make_float4(v * wdv.x, v * wdv.y, v * wdv.z, v * wdv.w);
    sacc = wave_sum4(sacc);
    dacc = wave_sum4(dacc);
    if (c == 0) { asrc4[node] = sacc; adst4[node] = dacc; }
}

// ---------------------------------------------------------------------------
extern "C" void kernel_launch(void* const* d_in, const int* in_sizes, int n_in,
                              void* d_out, int out_size, void* d_ws, size_t ws_size,
                              hipStream_t stream) {
    const float* x      = (const float*)d_in[0];
    const int*   ei     = (const int*)  d_in[1];
    const float* W1     = (const float*)d_in[2];
    const float* a1s    = (const float*)d_in[3];
    const float* a1d    = (const float*)d_in[4];
    const float* b1     = (const float*)d_in[5];
    const float* W2     = (const float*)d_in[6];
    const float* a2s    = (const float*)d_in[7];
    const float* a2d    = (const float*)d_in[8];
    const float* b2     = (const float*)d_in[9];
    const float* W3     = (const float*)d_in[10];
    const float* a3s    = (const float*)d_in[11];
    const float* a3d    = (const float*)d_in[12];
    const float* b3     = (const float*)d_in[13];
    const float* lin_w  = (const float*)d_in[14];
    const float* lin_b  = (const float*)d_in[15];

    const int N = in_sizes[0] / 3;
    const int E = in_sizes[1] / 2;
    const int Et = E + N;
    const int* src = ei;
    const int* dst = ei + E;
    const float scale8 = 8.0f / (float)N;
    const int vec_ok = ((((size_t)src | (size_t)dst) & 15) == 0) ? 1 : 0;

    // ---- workspace layout (xq first for 16B alignment) ----
    float* xq_f   = (float*)d_ws;                         // N*4 (float4)
    unsigned short* zb  = (unsigned short*)(xq_f + (size_t)N * 4);  // N*256
    unsigned short* xpA = zb  + (size_t)N * HC;           // N*64
    unsigned short* xpB = xpA + (size_t)N * CH;           // N*64
    unsigned short* Wb2 = xpB + (size_t)N * CH;           // 16384
    unsigned short* Wb3 = Wb2 + 16384;                    // 16384
    float* bufA   = (float*)(Wb3 + 16384);                // N*64
    float* bufB   = bufA + (size_t)N * CH;                // N*64
    float* zl     = bufB + (size_t)N * CH;                // N*16
    float* asrc   = zl   + (size_t)N * 16;                // N*4
    float* adst   = asrc + (size_t)N * 4;                 // N*4
    float* ws1    = adst + (size_t)N * 4;                 // 16
    float* wd1    = ws1 + 16;                             // 16
    float* ws2    = wd1 + 16;                             // 256
    float* wd2    = ws2 + 256;                            // 256
    float* ws3    = wd2 + 256;                            // 256
    float* wd3    = ws3 + 256;                            // 256
    int* deg      = (int*)(wd3 + 256);                    // N
    int* off      = deg + N;                              // N+4
    int* bsum     = off + N + 4;                          // 256
    int* slot     = bsum + 256;                           // E
    int* csr_src  = slot + E;                             // Et

    const int B = 256;
    const int G = (N + 255) / 256;
    const int EB4 = (E + 3) / 4;                 // 4 edges per thread
    const int CB = (EB4 + B - 1) / B;

    // ---- CSR build ----
    hipMemsetAsync(deg, 0, (size_t)N * sizeof(int), stream);
    count_kernel<<<CB * 8, B, 0, stream>>>(dst, E, vec_ok, scale8, deg, slot);
    scan_blocks<<<G, B, 0, stream>>>(deg, off, bsum, x, (float4*)xq_f, N);
    scan_bsums<<<1, B, 0, stream>>>(bsum, G, off + N);
    scan_add<<<G, B, 0, stream>>>(off, bsum, deg, csr_src, N);
    scatter_plain<<<CB, B, 0, stream>>>(src, dst, slot, E, vec_ok, off, csr_src);

    // ---- all weight prep in one launch ----
    prep_all<<<133, B, 0, stream>>>(W1, a1s, a1d, ws1, wd1,
                                    W2, a2s, a2d, Wb2, ws2, wd2,
                                    W3, a3s, a3d, Wb3, ws3, wd3);

    int nwave_blocks = (N * 64 + B - 1) / B;   // wave per node
    int ngemm_blocks = (N + 63) / 64;          // 64 nodes per block

    // ---- Layer 1 (split: 4-lane agg + wave-node epilogue; both measured) ----
    fused1_kernel<<<(N * 4 + B - 1) / B, B, 0, stream>>>(
        off, csr_src, (const float4*)xq_f, ws1, wd1, (float4*)zl, N);
    epi1_kernel<<<nwave_blocks, B, 0, stream>>>(
        (const float4*)zl, W1, b1, (const float4*)ws2, (const float4*)wd2,
        (float4*)asrc, (float4*)adst, bufA, xpA, N);

    // ---- Layer 2 (gemm epilogue folds layer-3 logits) ----
    agg_kernel<<<nwave_blocks, B, 0, stream>>>(
        off, csr_src, xpA, (const float4*)asrc, (const float4*)adst,
        zb, N);
    gemm_mfma<<<ngemm_blocks, B, 0, stream>>>(
        zb, Wb2, b2, bufA, (const float4*)ws3, (const float4*)wd3,
        (float4*)asrc, (float4*)adst,
        nullptr, nullptr, bufB, xpB, nullptr, N);

    // ---- Layer 3 (+ fused final linear) ----
    agg_kernel<<<nwave_blocks, B, 0, stream>>>(
        off, csr_src, xpB, (const float4*)asrc, (const float4*)adst,
        zb, N);
    gemm_mfma<<<ngemm_blocks, B, 0, stream>>>(
        zb, Wb3, b3, bufB, nullptr, nullptr, nullptr, nullptr,
        lin_w, lin_b, nullptr, nullptr, (float*)d_out, N);
}

// Round 10
// 312.033 us; speedup vs baseline: 1.1274x; 1.0248x over previous
//
#include <hip/hip_runtime.h>
#include <math.h>

#define HEADS 4
#define CH 64
#define HC 256   // HEADS*CH

typedef __attribute__((ext_vector_type(8))) short bf16x8;
typedef __attribute__((ext_vector_type(4))) float f32x4;

__device__ __forceinline__ float lrelu(float v) { return v > 0.f ? v : 0.2f * v; }

// fp32 -> bf16 bits, round-to-nearest-even
__device__ __forceinline__ unsigned int f2bf(float f) {
    unsigned int u = __float_as_uint(f);
    u += 0x7fffu + ((u >> 16) & 1u);
    return u >> 16;
}
__device__ __forceinline__ float bf2f(unsigned short u) {
    return __uint_as_float(((unsigned int)u) << 16);
}

__device__ __forceinline__ float4 wave_sum4(float4 v) {
#pragma unroll
    for (int m = 32; m; m >>= 1) {
        v.x += __shfl_xor(v.x, m);
        v.y += __shfl_xor(v.y, m);
        v.z += __shfl_xor(v.z, m);
        v.w += __shfl_xor(v.w, m);
    }
    return v;
}

// ---------------------------------------------------------------------------
// CSR build. count is XCD-affine and RECORDS each edge's slot (atomicAdd
// return) so scatter needs no atomics and no replication.
__global__ void count_kernel(const int* __restrict__ dst, int E, int vec_ok,
                             float scale8, int* __restrict__ deg,
                             int* __restrict__ slot) {
    int r = blockIdx.x & 7;
    int i = (blockIdx.x >> 3) * blockDim.x + threadIdx.x;
    int e0 = i * 4;
    if (e0 >= E) return;
    int d[4];
    int cnt;
    if (vec_ok && e0 + 3 < E) {
        int4 v = *(const int4*)(dst + e0);
        d[0] = v.x; d[1] = v.y; d[2] = v.z; d[3] = v.w; cnt = 4;
    } else {
        cnt = min(4, E - e0);
        for (int k = 0; k < cnt; ++k) d[k] = dst[e0 + k];
    }
    for (int k = 0; k < cnt; ++k) {
        int rr = min(7, (int)((float)d[k] * scale8));
        if (rr == r) slot[e0 + k] = atomicAdd(&deg[d[k]], 1);
    }
}

// scan pass 1 (+ float4-pack x: this grid is exactly N threads).
// Prefixes deg[g]+1 — the +1 is the implicit self-loop.
__global__ void scan_blocks(const int* __restrict__ deg,
                            int* __restrict__ off,
                            int* __restrict__ bsum,
                            const float* __restrict__ x,
                            float4* __restrict__ xq, int N) {
    __shared__ int sh[256];
    int t = threadIdx.x;
    int g = blockIdx.x * 256 + t;
    int v = (g < N) ? deg[g] + 1 : 0;
    if (g < N) xq[g] = make_float4(x[3 * g], x[3 * g + 1], x[3 * g + 2], 0.f);
    sh[t] = v;
    __syncthreads();
    for (int d = 1; d < 256; d <<= 1) {
        int xv = (t >= d) ? sh[t - d] : 0;
        __syncthreads();
        sh[t] += xv;
        __syncthreads();
    }
    if (g < N) off[g] = sh[t] - v;
    if (t == 255) bsum[blockIdx.x] = sh[255];
}

// scan pass 2+3 in ONE kernel: each block redundantly computes the prefix of
// bsum[0..bid) (cheap: <=G int reads + LDS tree), then finalizes off and
// plain-stores the self-loop into the node's LAST slot.  Last node writes
// off[N].  (Replaces the scan_bsums dispatch.)
__global__ void scan_add(int* __restrict__ off, const int* __restrict__ bsum,
                         const int* __restrict__ deg,
                         int* __restrict__ csr_src, int N) {
    __shared__ int sh[256];
    int t = threadIdx.x, bid = blockIdx.x;
    int s = 0;
    for (int i = t; i < bid; i += 256) s += bsum[i];
    sh[t] = s;
    __syncthreads();
    for (int d = 128; d > 0; d >>= 1) {
        if (t < d) sh[t] += sh[t + d];
        __syncthreads();
    }
    int base = sh[0];
    int g = bid * 256 + t;
    if (g < N) {
        int o = off[g] + base;
        off[g] = o;
        int dg = deg[g];
        csr_src[o + dg] = g;
        if (g == N - 1) off[N] = o + dg + 1;
    }
}

// ---------------------------------------------------------------------------
// Atomic-free scatter MERGED with all weight prep (independent work; one
// dispatch by blockIdx range).
__device__ __forceinline__ void prep_blk(int b, int t, const float* W,
                                         const float* a_s, const float* a_d,
                                         unsigned short* Wb, float* ws,
                                         float* wd) {
    if (b < 64) {
        Wb[b * 256 + t] = (unsigned short)f2bf(W[(t >> 2) * HC + (t & 3) * CH + b]);
    } else {
        int idx = (b - 64) * 256 + t;      // 0..511
        int which = idx >= 256;
        int i = which ? idx - 256 : idx;   // i = k*4+h
        int k = i >> 2, h = i & 3;
        const float* av = (which ? a_d : a_s) + h * CH;
        const float* Wr = W + (size_t)k * HC + h * CH;
        float s = 0.f;
        for (int c = 0; c < CH; ++c) s += Wr[c] * av[c];
        (which ? wd : ws)[i] = s;
    }
}

__global__ void scatter_prep(const int* __restrict__ src,
                             const int* __restrict__ dst,
                             const int* __restrict__ slot, int E, int vec_ok,
                             const int* __restrict__ off,
                             int* __restrict__ csr_src, int CB,
                             const float* __restrict__ W1,
                             const float* __restrict__ a1s,
                             const float* __restrict__ a1d,
                             float* __restrict__ ws1, float* __restrict__ wd1,
                             const float* __restrict__ W2,
                             const float* __restrict__ a2s,
                             const float* __restrict__ a2d,
                             unsigned short* __restrict__ Wb2,
                             float* __restrict__ ws2, float* __restrict__ wd2,
                             const float* __restrict__ W3,
                             const float* __restrict__ a3s,
                             const float* __restrict__ a3d,
                             unsigned short* __restrict__ Wb3,
                             float* __restrict__ ws3, float* __restrict__ wd3) {
    int bid = blockIdx.x;
    int t = threadIdx.x;
    if (bid < CB) {
        int e0 = (bid * blockDim.x + t) * 4;
        if (e0 >= E) return;
        if (vec_ok && e0 + 3 < E) {
            int4 sv = *(const int4*)(src + e0);
            int4 dv = *(const int4*)(dst + e0);
            int4 pv = *(const int4*)(slot + e0);
            csr_src[off[dv.x] + pv.x] = sv.x;
            csr_src[off[dv.y] + pv.y] = sv.y;
            csr_src[off[dv.z] + pv.z] = sv.z;
            csr_src[off[dv.w] + pv.w] = sv.w;
        } else {
            int cnt = min(4, E - e0);
            for (int k = 0; k < cnt; ++k) {
                int e = e0 + k;
                csr_src[off[dst[e]] + slot[e]] = src[e];
            }
        }
        return;
    }
    int b = bid - CB;
    if (b < 66) {
        prep_blk(b, t, W2, a2s, a2d, Wb2, ws2, wd2);
    } else if (b < 132) {
        prep_blk(b - 66, t, W3, a3s, a3d, Wb3, ws3, wd3);
    } else {
        for (int idx = t; idx < 24; idx += blockDim.x) {
            int which = idx >= 12;
            int i = which ? idx - 12 : idx;
            int k = i >> 2, h = i & 3;
            const float* av = (which ? a1d : a1s) + h * CH;
            const float* Wr = W1 + (size_t)k * HC + h * CH;
            float s = 0.f;
            for (int c = 0; c < CH; ++c) s += Wr[c] * av[c];
            (which ? wd1 : ws1)[i] = s;
        }
    }
}

// ---------------------------------------------------------------------------
// Layer 1, one kernel, TWO phases with distinct parallelism shapes:
// phase A: 4 lanes/node gather+logits (fused1 structure, unchanged) -> z,l
//          via 4-lane xor reduce -> 4KB LDS (16 floats per node).
// phase B: after barrier, each wave epilogues 16 nodes with lane=CHANNEL —
//          coalesced 256B row writes (round-7's merge failed precisely
//          because its epilogue wrote 16B fragments at 64B stride).
__global__ void l1_kernel(const int* __restrict__ off,
                          const int* __restrict__ csr_src,
                          const float4* __restrict__ xq,
                          const float* __restrict__ ws,   // ws1[12], k*4+h
                          const float* __restrict__ wd,   // wd1[12]
                          const float* __restrict__ W1,
                          const float* __restrict__ b1,
                          const float4* __restrict__ ws2_4,
                          const float4* __restrict__ wd2_4,
                          float4* __restrict__ asrc4,
                          float4* __restrict__ adst4,
                          float* __restrict__ out,
                          unsigned short* __restrict__ out_pack, int N) {
    __shared__ float zsh[64][16];   // 4KB: z[12] + l[4] per node
    int t = threadIdx.x;
    int ln = t >> 2, j = t & 3;
    int node = blockIdx.x * 64 + ln;

    if (node < N) {
        float4 xn = xq[node];
        float ad0 = xn.x * wd[0] + xn.y * wd[4] + xn.z * wd[8];
        float ad1 = xn.x * wd[1] + xn.y * wd[5] + xn.z * wd[9];
        float ad2 = xn.x * wd[2] + xn.y * wd[6] + xn.z * wd[10];
        float ad3 = xn.x * wd[3] + xn.y * wd[7] + xn.z * wd[11];

        int o0 = off[node], o1 = off[node + 1];
        float z[12];
#pragma unroll
        for (int q = 0; q < 12; ++q) z[q] = 0.f;
        float l0 = 0.f, l1 = 0.f, l2 = 0.f, l3 = 0.f;

        for (int i = o0 + j; i < o1; i += 4) {
            int s = csr_src[i];
            float4 xv = xq[s];
            float e0 = __expf(lrelu(xv.x * ws[0] + xv.y * ws[4] + xv.z * ws[8]  + ad0));
            float e1 = __expf(lrelu(xv.x * ws[1] + xv.y * ws[5] + xv.z * ws[9]  + ad1));
            float e2 = __expf(lrelu(xv.x * ws[2] + xv.y * ws[6] + xv.z * ws[10] + ad2));
            float e3 = __expf(lrelu(xv.x * ws[3] + xv.y * ws[7] + xv.z * ws[11] + ad3));
            l0 += e0; l1 += e1; l2 += e2; l3 += e3;
            z[0] += e0 * xv.x; z[1]  += e0 * xv.y; z[2]  += e0 * xv.z;
            z[3] += e1 * xv.x; z[4]  += e1 * xv.y; z[5]  += e1 * xv.z;
            z[6] += e2 * xv.x; z[7]  += e2 * xv.y; z[8]  += e2 * xv.z;
            z[9] += e3 * xv.x; z[10] += e3 * xv.y; z[11] += e3 * xv.z;
        }
#pragma unroll
        for (int m = 1; m < 4; m <<= 1) {
#pragma unroll
            for (int q = 0; q < 12; ++q) z[q] += __shfl_xor(z[q], m);
            l0 += __shfl_xor(l0, m);
            l1 += __shfl_xor(l1, m);
            l2 += __shfl_xor(l2, m);
            l3 += __shfl_xor(l3, m);
        }
        float4 wv;
        if (j == 0)      wv = make_float4(z[0], z[1], z[2],  z[3]);
        else if (j == 1) wv = make_float4(z[4], z[5], z[6],  z[7]);
        else if (j == 2) wv = make_float4(z[8], z[9], z[10], z[11]);
        else             wv = make_float4(l0, l1, l2, l3);
        *(float4*)&zsh[ln][j * 4] = wv;
    }
    __syncthreads();

    // ---- phase B: wave per node, lane = channel ----
    int w = t >> 6, c = t & 63;
    for (int ii = 0; ii < 16; ++ii) {
        int ln2 = w * 16 + ii;
        int n2 = blockIdx.x * 64 + ln2;
        if (n2 >= N) break;
        float4 z0 = *(const float4*)&zsh[ln2][0];
        float4 z1 = *(const float4*)&zsh[ln2][4];
        float4 z2 = *(const float4*)&zsh[ln2][8];
        float4 l4 = *(const float4*)&zsh[ln2][12];
        float i0 = 0.25f / l4.x, i1 = 0.25f / l4.y;
        float i2 = 0.25f / l4.z, i3 = 0.25f / l4.w;
        float acc =
            (z0.x * W1[0 * HC +   0 + c] + z0.y * W1[1 * HC +   0 + c] + z0.z * W1[2 * HC +   0 + c]) * i0 +
            (z0.w * W1[0 * HC +  64 + c] + z1.x * W1[1 * HC +  64 + c] + z1.y * W1[2 * HC +  64 + c]) * i1 +
            (z1.z * W1[0 * HC + 128 + c] + z1.w * W1[1 * HC + 128 + c] + z2.x * W1[2 * HC + 128 + c]) * i2 +
            (z2.y * W1[0 * HC + 192 + c] + z2.z * W1[1 * HC + 192 + c] + z2.w * W1[2 * HC + 192 + c]) * i3;
        float v = acc + b1[c];
        v = v > 0.f ? v : expm1f(v);
        out[(size_t)n2 * CH + c] = v;
        out_pack[(size_t)n2 * CH + c] = (unsigned short)f2bf(v);
        float4 wsv = ws2_4[c], wdv = wd2_4[c];
        float4 sacc = make_float4(v * wsv.x, v * wsv.y, v * wsv.z, v * wsv.w);
        float4 dacc = make_float4(v * wdv.x, v * wdv.y, v * wdv.z, v * wdv.w);
        sacc = wave_sum4(sacc);
        dacc = wave_sum4(dacc);
        if (c == 0) { asrc4[n2] = sacc; adst4[n2] = dacc; }
    }
}

// ---------------------------------------------------------------------------
// Input-space aggregation (layers 2/3): wave per dst node, 2 edges/iter
// (half-wave per edge, 2 k-columns per lane).  l accumulated in phase 2 from
// the LDS-broadcast exe (replaces the 24-shuffle wave_sum4 with 4 extra
// shuffles in the final xor-32 combine).
__global__ void agg_kernel(const int* __restrict__ off,
                           const int* __restrict__ csr_src,
                           const unsigned short* __restrict__ xp,
                           const float4* __restrict__ asrc4,
                           const float4* __restrict__ adst4,
                           unsigned short* __restrict__ zb, int N) {
    __shared__ float4 exs[4][64];
    __shared__ unsigned int sss[4][64];
    int node = (blockIdx.x * blockDim.x + threadIdx.x) >> 6;
    int w = (threadIdx.x >> 6) & 3;
    int lane = threadIdx.x & 63;
    if (node >= N) return;
    int half = lane >> 5;          // which edge of the pair
    int lk = lane & 31;            // k-pair index: k = 2*lk, 2*lk+1
    int o0 = off[node], o1 = off[node + 1];
    int deg = o1 - o0;
    float4 ad = adst4[node];

    float l0 = 0.f, l1 = 0.f, l2 = 0.f, l3 = 0.f;
    float z[8];
#pragma unroll
    for (int q = 0; q < 8; ++q) z[q] = 0.f;
    const char* xpb2 = (const char*)xp + lk * 4;

    for (int base = 0; base < deg; base += 64) {
        int i = base + lane;
        int s = 0;
        float4 ev = make_float4(-INFINITY, -INFINITY, -INFINITY, -INFINITY);
        if (i < deg) {
            s = csr_src[o0 + i];
            float4 as = asrc4[s];
            ev.x = lrelu(as.x + ad.x);
            ev.y = lrelu(as.y + ad.y);
            ev.z = lrelu(as.z + ad.z);
            ev.w = lrelu(as.w + ad.w);
        }
        float4 ex;
        ex.x = __expf(ev.x);   // inactive lanes: exp(-inf) = 0
        ex.y = __expf(ev.y);
        ex.z = __expf(ev.z);
        ex.w = __expf(ev.w);
        exs[w][lane] = ex;
        sss[w][lane] = (unsigned)s * 128u;   // byte offset of row s in xp

        int cnt = min(64, deg - base);
        // 2 edges per iteration; tail edge (e==cnt) has exe==0.
#pragma unroll 2
        for (int e2 = 0; e2 < cnt; e2 += 2) {
            int e = e2 + half;
            unsigned soff = sss[w][e];       // 2-addr LDS broadcast (free)
            float4 exe = exs[w][e];
            l0 += exe.x; l1 += exe.y; l2 += exe.z; l3 += exe.w;
            unsigned xx = *(const unsigned*)(xpb2 + soff);
            float xk0 = bf2f((unsigned short)(xx & 0xffffu));
            float xk1 = bf2f((unsigned short)(xx >> 16));
            z[0] += exe.x * xk0; z[1] += exe.y * xk0;
            z[2] += exe.z * xk0; z[3] += exe.w * xk0;
            z[4] += exe.x * xk1; z[5] += exe.y * xk1;
            z[6] += exe.z * xk1; z[7] += exe.w * xk1;
        }
    }
    // combine even/odd edge chains across the two halves
#pragma unroll
    for (int q = 0; q < 8; ++q) z[q] += __shfl_xor(z[q], 32);
    l0 += __shfl_xor(l0, 32);
    l1 += __shfl_xor(l1, 32);
    l2 += __shfl_xor(l2, 32);
    l3 += __shfl_xor(l3, 32);

    float s0 = 0.25f / l0, s1 = 0.25f / l1, s2 = 0.25f / l2, s3 = 0.25f / l3;
    if (half == 0) {
        uint4 zo;   // zb[node][j], j=k*4+h: k0 -> j=8lk.., k1 -> j=8lk+4..
        zo.x = f2bf(z[0] * s0) | (f2bf(z[1] * s1) << 16);
        zo.y = f2bf(z[2] * s2) | (f2bf(z[3] * s3) << 16);
        zo.z = f2bf(z[4] * s0) | (f2bf(z[5] * s1) << 16);
        zo.w = f2bf(z[6] * s2) | (f2bf(z[7] * s3) << 16);
        *(uint4*)((char*)zb + (size_t)node * 512 + lk * 16) = zo;
    }
}

// ---------------------------------------------------------------------------
// MFMA post-aggregation GEMM (layers 2/3). A = zb (bf16 [n][j], j=k*4+h),
// B = Wb (bf16 [c][j]).  Layer-2 epilogue folds layer-3 logits; layer 3
// folds the final linear.
__global__ void gemm_mfma(const unsigned short* __restrict__ zb,
                          const unsigned short* __restrict__ Wb,
                          const float* __restrict__ bias,
                          const float* __restrict__ residual,
                          const float4* __restrict__ wsn4,
                          const float4* __restrict__ wdn4,
                          float4* __restrict__ asrc4,
                          float4* __restrict__ adst4,
                          const float* __restrict__ lin_w,
                          const float* __restrict__ lin_b,
                          float* __restrict__ out_f32,
                          unsigned short* __restrict__ out_pack,
                          float* __restrict__ out_final, int N) {
    int w = threadIdx.x >> 6;
    int lane = threadIdx.x & 63;
    int quad = lane >> 4, col = lane & 15;
    int nbase = blockIdx.x * 64 + w * 16;

    f32x4 zero4 = {0.f, 0.f, 0.f, 0.f};
    f32x4 acc[4];
#pragma unroll
    for (int t = 0; t < 4; ++t) acc[t] = zero4;

    const unsigned short* arow = zb + (size_t)(nbase + col) * HC + quad * 8;
#pragma unroll
    for (int q = 0; q < 8; ++q) {
        bf16x8 af = *(const bf16x8*)(arow + q * 32);
#pragma unroll
        for (int t = 0; t < 4; ++t) {
            const unsigned short* bp = Wb + (size_t)(t * 16 + col) * HC + q * 32 + quad * 8;
            bf16x8 bfrag = *(const bf16x8*)bp;
            acc[t] = __builtin_amdgcn_mfma_f32_16x16x32_bf16(af, bfrag, acc[t], 0, 0, 0);
        }
    }

    if (!out_final) {
        float vv[4][4];   // [t][r]
#pragma unroll
        for (int t = 0; t < 4; ++t) {
            int c = t * 16 + col;
            float bc = bias[c];
#pragma unroll
            for (int r = 0; r < 4; ++r) {
                int n = nbase + quad * 4 + r;
                float v = acc[t][r] + bc;
                v = v > 0.f ? v : expm1f(v);
                v += residual[(size_t)n * CH + c];
                vv[t][r] = v;
                if (n < N) {
                    out_f32[(size_t)n * CH + c] = v;
                    out_pack[(size_t)n * CH + c] = (unsigned short)f2bf(v);
                }
            }
        }
        float4 wsv[4], wdv[4];
#pragma unroll
        for (int t = 0; t < 4; ++t) { wsv[t] = wsn4[t * 16 + col]; wdv[t] = wdn4[t * 16 + col]; }
#pragma unroll
        for (int r = 0; r < 4; ++r) {
            int n = nbase + quad * 4 + r;
            float4 sa = make_float4(0.f, 0.f, 0.f, 0.f);
            float4 da = make_float4(0.f, 0.f, 0.f, 0.f);
#pragma unroll
            for (int t = 0; t < 4; ++t) {
                float v = vv[t][r];
                sa.x += v * wsv[t].x; sa.y += v * wsv[t].y;
                sa.z += v * wsv[t].z; sa.w += v * wsv[t].w;
                da.x += v * wdv[t].x; da.y += v * wdv[t].y;
                da.z += v * wdv[t].z; da.w += v * wdv[t].w;
            }
#pragma unroll
            for (int m = 8; m; m >>= 1) {
                sa.x += __shfl_xor(sa.x, m); sa.y += __shfl_xor(sa.y, m);
                sa.z += __shfl_xor(sa.z, m); sa.w += __shfl_xor(sa.w, m);
                da.x += __shfl_xor(da.x, m); da.y += __shfl_xor(da.y, m);
                da.z += __shfl_xor(da.z, m); da.w += __shfl_xor(da.w, m);
            }
            if (col == 0 && n < N) { asrc4[n] = sa; adst4[n] = da; }
        }
    } else {
        float lw[4], bb[4];
#pragma unroll
        for (int t = 0; t < 4; ++t) { lw[t] = lin_w[t * 16 + col]; bb[t] = bias[t * 16 + col]; }
#pragma unroll
        for (int r = 0; r < 4; ++r) {
            int n = nbase + quad * 4 + r;
            float ts = 0.f;
#pragma unroll
            for (int t = 0; t < 4; ++t) {
                float v = acc[t][r] + bb[t];
                v = v > 0.f ? v : expm1f(v);
                v += residual[(size_t)n * CH + (t * 16 + col)];
                ts += v * lw[t];
            }
            ts += __shfl_xor(ts, 1);
            ts += __shfl_xor(ts, 2);
            ts += __shfl_xor(ts, 4);
            ts += __shfl_xor(ts, 8);
            if (col == 0 && n < N) out_final[n] = ts + lin_b[0];
        }
    }
}

// ---------------------------------------------------------------------------
extern "C" void kernel_launch(void* const* d_in, const int* in_sizes, int n_in,
                              void* d_out, int out_size, void* d_ws, size_t ws_size,
                              hipStream_t stream) {
    const float* x      = (const float*)d_in[0];
    const int*   ei     = (const int*)  d_in[1];
    const float* W1     = (const float*)d_in[2];
    const float* a1s    = (const float*)d_in[3];
    const float* a1d    = (const float*)d_in[4];
    const float* b1     = (const float*)d_in[5];
    const float* W2     = (const float*)d_in[6];
    const float* a2s    = (const float*)d_in[7];
    const float* a2d    = (const float*)d_in[8];
    const float* b2     = (const float*)d_in[9];
    const float* W3     = (const float*)d_in[10];
    const float* a3s    = (const float*)d_in[11];
    const float* a3d    = (const float*)d_in[12];
    const float* b3     = (const float*)d_in[13];
    const float* lin_w  = (const float*)d_in[14];
    const float* lin_b  = (const float*)d_in[15];

    const int N = in_sizes[0] / 3;
    const int E = in_sizes[1] / 2;
    const int Et = E + N;
    const int* src = ei;
    const int* dst = ei + E;
    const float scale8 = 8.0f / (float)N;
    const int vec_ok = ((((size_t)src | (size_t)dst) & 15) == 0) ? 1 : 0;

    // ---- workspace layout (xq first for 16B alignment) ----
    float* xq_f   = (float*)d_ws;                         // N*4 (float4)
    unsigned short* zb  = (unsigned short*)(xq_f + (size_t)N * 4);  // N*256
    unsigned short* xpA = zb  + (size_t)N * HC;           // N*64
    unsigned short* xpB = xpA + (size_t)N * CH;           // N*64
    unsigned short* Wb2 = xpB + (size_t)N * CH;           // 16384
    unsigned short* Wb3 = Wb2 + 16384;                    // 16384
    float* bufA   = (float*)(Wb3 + 16384);                // N*64
    float* bufB   = bufA + (size_t)N * CH;                // N*64
    float* asrc   = bufB + (size_t)N * CH;                // N*4
    float* adst   = asrc + (size_t)N * 4;                 // N*4
    float* ws1    = adst + (size_t)N * 4;                 // 16
    float* wd1    = ws1 + 16;                             // 16
    float* ws2    = wd1 + 16;                             // 256
    float* wd2    = ws2 + 256;                            // 256
    float* ws3    = wd2 + 256;                            // 256
    float* wd3    = ws3 + 256;                            // 256
    int* deg      = (int*)(wd3 + 256);                    // N
    int* off      = deg + N;                              // N+4
    int* bsum     = off + N + 4;                          // 1024
    int* slot     = bsum + 1024;                          // E
    int* csr_src  = slot + E;                             // Et

    const int B = 256;
    const int G = (N + 255) / 256;
    const int EB4 = (E + 3) / 4;                 // 4 edges per thread
    const int CB = (EB4 + B - 1) / B;

    // ---- CSR build + weight prep (5 dispatches incl memset) ----
    hipMemsetAsync(deg, 0, (size_t)N * sizeof(int), stream);
    count_kernel<<<CB * 8, B, 0, stream>>>(dst, E, vec_ok, scale8, deg, slot);
    scan_blocks<<<G, B, 0, stream>>>(deg, off, bsum, x, (float4*)xq_f, N);
    scan_add<<<G, B, 0, stream>>>(off, bsum, deg, csr_src, N);
    scatter_prep<<<CB + 133, B, 0, stream>>>(
        src, dst, slot, E, vec_ok, off, csr_src, CB,
        W1, a1s, a1d, ws1, wd1,
        W2, a2s, a2d, Wb2, ws2, wd2,
        W3, a3s, a3d, Wb3, ws3, wd3);

    int nwave_blocks = (N * 64 + B - 1) / B;   // wave per node (agg)
    int ngemm_blocks = (N + 63) / 64;          // 64 nodes per block

    // ---- Layer 1 (one kernel: gather phase + coalesced wave-epilogue) ----
    l1_kernel<<<ngemm_blocks, B, 0, stream>>>(
        off, csr_src, (const float4*)xq_f, ws1, wd1, W1, b1,
        (const float4*)ws2, (const float4*)wd2,
        (float4*)asrc, (float4*)adst, bufA, xpA, N);

    // ---- Layer 2 (gemm epilogue folds layer-3 logits) ----
    agg_kernel<<<nwave_blocks, B, 0, stream>>>(
        off, csr_src, xpA, (const float4*)asrc, (const float4*)adst,
        zb, N);
    gemm_mfma<<<ngemm_blocks, B, 0, stream>>>(
        zb, Wb2, b2, bufA, (const float4*)ws3, (const float4*)wd3,
        (float4*)asrc, (float4*)adst,
        nullptr, nullptr, bufB, xpB, nullptr, N);

    // ---- Layer 3 (+ fused final linear) ----
    agg_kernel<<<nwave_blocks, B, 0, stream>>>(
        off, csr_src, xpB, (const float4*)asrc, (const float4*)adst,
        zb, N);
    gemm_mfma<<<ngemm_blocks, B, 0, stream>>>(
        zb, Wb3, b3, bufB, nullptr, nullptr, nullptr, nullptr,
        lin_w, lin_b, nullptr, nullptr, (float*)d_out, N);
}

// Round 11
// 303.100 us; speedup vs baseline: 1.1606x; 1.0295x over previous
//
#include <hip/hip_runtime.h>
#include <math.h>

#define HEADS 4
#define CH 64
#define HC 256   // HEADS*CH

typedef __attribute__((ext_vector_type(8))) short bf16x8;
typedef __attribute__((ext_vector_type(4))) float f32x4;

__device__ __forceinline__ float lrelu(float v) { return v > 0.f ? v : 0.2f * v; }

// fp32 -> bf16 bits, round-to-nearest-even
__device__ __forceinline__ unsigned int f2bf(float f) {
    unsigned int u = __float_as_uint(f);
    u += 0x7fffu + ((u >> 16) & 1u);
    return u >> 16;
}
__device__ __forceinline__ float bf2f(unsigned short u) {
    return __uint_as_float(((unsigned int)u) << 16);
}

__device__ __forceinline__ float4 wave_sum4(float4 v) {
#pragma unroll
    for (int m = 32; m; m >>= 1) {
        v.x += __shfl_xor(v.x, m);
        v.y += __shfl_xor(v.y, m);
        v.z += __shfl_xor(v.z, m);
        v.w += __shfl_xor(v.w, m);
    }
    return v;
}

// ---------------------------------------------------------------------------
// CSR build. count is XCD-affine and RECORDS each edge's slot (atomicAdd
// return) so scatter needs no atomics and no replication.
__global__ void count_kernel(const int* __restrict__ dst, int E, int vec_ok,
                             float scale8, int* __restrict__ deg,
                             int* __restrict__ slot) {
    int r = blockIdx.x & 7;
    int i = (blockIdx.x >> 3) * blockDim.x + threadIdx.x;
    int e0 = i * 4;
    if (e0 >= E) return;
    int d[4];
    int cnt;
    if (vec_ok && e0 + 3 < E) {
        int4 v = *(const int4*)(dst + e0);
        d[0] = v.x; d[1] = v.y; d[2] = v.z; d[3] = v.w; cnt = 4;
    } else {
        cnt = min(4, E - e0);
        for (int k = 0; k < cnt; ++k) d[k] = dst[e0 + k];
    }
    for (int k = 0; k < cnt; ++k) {
        int rr = min(7, (int)((float)d[k] * scale8));
        if (rr == r) slot[e0 + k] = atomicAdd(&deg[d[k]], 1);
    }
}

// scan pass 1 (+ float4-pack x: this grid is exactly N threads).
// Prefixes deg[g]+1 — the +1 is the implicit self-loop.
__global__ void scan_blocks(const int* __restrict__ deg,
                            int* __restrict__ off,
                            int* __restrict__ bsum,
                            const float* __restrict__ x,
                            float4* __restrict__ xq, int N) {
    __shared__ int sh[256];
    int t = threadIdx.x;
    int g = blockIdx.x * 256 + t;
    int v = (g < N) ? deg[g] + 1 : 0;
    if (g < N) xq[g] = make_float4(x[3 * g], x[3 * g + 1], x[3 * g + 2], 0.f);
    sh[t] = v;
    __syncthreads();
    for (int d = 1; d < 256; d <<= 1) {
        int xv = (t >= d) ? sh[t - d] : 0;
        __syncthreads();
        sh[t] += xv;
        __syncthreads();
    }
    if (g < N) off[g] = sh[t] - v;
    if (t == 255) bsum[blockIdx.x] = sh[255];
}

// scan pass 2+3 in ONE kernel: each block redundantly computes the prefix of
// bsum[0..bid), finalizes off, and plain-stores the self-loop into the
// node's LAST slot.  Last node writes off[N].
__global__ void scan_add(int* __restrict__ off, const int* __restrict__ bsum,
                         const int* __restrict__ deg,
                         int* __restrict__ csr_src, int N) {
    __shared__ int sh[256];
    int t = threadIdx.x, bid = blockIdx.x;
    int s = 0;
    for (int i = t; i < bid; i += 256) s += bsum[i];
    sh[t] = s;
    __syncthreads();
    for (int d = 128; d > 0; d >>= 1) {
        if (t < d) sh[t] += sh[t + d];
        __syncthreads();
    }
    int base = sh[0];
    int g = bid * 256 + t;
    if (g < N) {
        int o = off[g] + base;
        off[g] = o;
        int dg = deg[g];
        csr_src[o + dg] = g;
        if (g == N - 1) off[N] = o + dg + 1;
    }
}

// ---------------------------------------------------------------------------
// Atomic-free scatter MERGED with all weight prep (independent work; one
// dispatch by blockIdx range).
__device__ __forceinline__ void prep_blk(int b, int t, const float* W,
                                         const float* a_s, const float* a_d,
                                         unsigned short* Wb, float* ws,
                                         float* wd) {
    if (b < 64) {
        Wb[b * 256 + t] = (unsigned short)f2bf(W[(t >> 2) * HC + (t & 3) * CH + b]);
    } else {
        int idx = (b - 64) * 256 + t;      // 0..511
        int which = idx >= 256;
        int i = which ? idx - 256 : idx;   // i = k*4+h
        int k = i >> 2, h = i & 3;
        const float* av = (which ? a_d : a_s) + h * CH;
        const float* Wr = W + (size_t)k * HC + h * CH;
        float s = 0.f;
        for (int c = 0; c < CH; ++c) s += Wr[c] * av[c];
        (which ? wd : ws)[i] = s;
    }
}

__global__ void scatter_prep(const int* __restrict__ src,
                             const int* __restrict__ dst,
                             const int* __restrict__ slot, int E, int vec_ok,
                             const int* __restrict__ off,
                             int* __restrict__ csr_src, int CB,
                             const float* __restrict__ W1,
                             const float* __restrict__ a1s,
                             const float* __restrict__ a1d,
                             float* __restrict__ ws1, float* __restrict__ wd1,
                             const float* __restrict__ W2,
                             const float* __restrict__ a2s,
                             const float* __restrict__ a2d,
                             unsigned short* __restrict__ Wb2,
                             float* __restrict__ ws2, float* __restrict__ wd2,
                             const float* __restrict__ W3,
                             const float* __restrict__ a3s,
                             const float* __restrict__ a3d,
                             unsigned short* __restrict__ Wb3,
                             float* __restrict__ ws3, float* __restrict__ wd3) {
    int bid = blockIdx.x;
    int t = threadIdx.x;
    if (bid < CB) {
        int e0 = (bid * blockDim.x + t) * 4;
        if (e0 >= E) return;
        if (vec_ok && e0 + 3 < E) {
            int4 sv = *(const int4*)(src + e0);
            int4 dv = *(const int4*)(dst + e0);
            int4 pv = *(const int4*)(slot + e0);
            csr_src[off[dv.x] + pv.x] = sv.x;
            csr_src[off[dv.y] + pv.y] = sv.y;
            csr_src[off[dv.z] + pv.z] = sv.z;
            csr_src[off[dv.w] + pv.w] = sv.w;
        } else {
            int cnt = min(4, E - e0);
            for (int k = 0; k < cnt; ++k) {
                int e = e0 + k;
                csr_src[off[dst[e]] + slot[e]] = src[e];
            }
        }
        return;
    }
    int b = bid - CB;
    if (b < 66) {
        prep_blk(b, t, W2, a2s, a2d, Wb2, ws2, wd2);
    } else if (b < 132) {
        prep_blk(b - 66, t, W3, a3s, a3d, Wb3, ws3, wd3);
    } else {
        for (int idx = t; idx < 24; idx += blockDim.x) {
            int which = idx >= 12;
            int i = which ? idx - 12 : idx;
            int k = i >> 2, h = i & 3;
            const float* av = (which ? a1d : a1s) + h * CH;
            const float* Wr = W1 + (size_t)k * HC + h * CH;
            float s = 0.f;
            for (int c = 0; c < CH; ++c) s += Wr[c] * av[c];
            (which ? wd1 : ws1)[i] = s;
        }
    }
}

// ---------------------------------------------------------------------------
// Layer-1 aggregation: 4 LANES per node (3125 waves; float4 x loads; logits
// inline).  Writes compact zl.  (Round-10's merged l1_kernel regressed to
// 53us: phase-B serialized 16 nodes/wave at 20% occupancy — split is faster.)
__global__ void fused1_kernel(const int* __restrict__ off,
                              const int* __restrict__ csr_src,
                              const float4* __restrict__ xq,
                              const float* __restrict__ ws,   // ws1[12], k*4+h
                              const float* __restrict__ wd,   // wd1[12]
                              float4* __restrict__ zl, int N) {
    int t = blockIdx.x * blockDim.x + threadIdx.x;
    int n = t >> 2, j = t & 3;
    if (n >= N) return;
    float4 xn = xq[n];
    float ad0 = xn.x * wd[0] + xn.y * wd[4] + xn.z * wd[8];
    float ad1 = xn.x * wd[1] + xn.y * wd[5] + xn.z * wd[9];
    float ad2 = xn.x * wd[2] + xn.y * wd[6] + xn.z * wd[10];
    float ad3 = xn.x * wd[3] + xn.y * wd[7] + xn.z * wd[11];

    int o0 = off[n], o1 = off[n + 1];
    float z[12];
#pragma unroll
    for (int q = 0; q < 12; ++q) z[q] = 0.f;
    float l0 = 0.f, l1 = 0.f, l2 = 0.f, l3 = 0.f;

    for (int i = o0 + j; i < o1; i += 4) {
        int s = csr_src[i];
        float4 xv = xq[s];
        float e0 = __expf(lrelu(xv.x * ws[0] + xv.y * ws[4] + xv.z * ws[8]  + ad0));
        float e1 = __expf(lrelu(xv.x * ws[1] + xv.y * ws[5] + xv.z * ws[9]  + ad1));
        float e2 = __expf(lrelu(xv.x * ws[2] + xv.y * ws[6] + xv.z * ws[10] + ad2));
        float e3 = __expf(lrelu(xv.x * ws[3] + xv.y * ws[7] + xv.z * ws[11] + ad3));
        l0 += e0; l1 += e1; l2 += e2; l3 += e3;
        z[0] += e0 * xv.x; z[1]  += e0 * xv.y; z[2]  += e0 * xv.z;
        z[3] += e1 * xv.x; z[4]  += e1 * xv.y; z[5]  += e1 * xv.z;
        z[6] += e2 * xv.x; z[7]  += e2 * xv.y; z[8]  += e2 * xv.z;
        z[9] += e3 * xv.x; z[10] += e3 * xv.y; z[11] += e3 * xv.z;
    }
    // reduce across the 4 lanes of this node
#pragma unroll
    for (int m = 1; m < 4; m <<= 1) {
#pragma unroll
        for (int q = 0; q < 12; ++q) z[q] += __shfl_xor(z[q], m);
        l0 += __shfl_xor(l0, m);
        l1 += __shfl_xor(l1, m);
        l2 += __shfl_xor(l2, m);
        l3 += __shfl_xor(l3, m);
    }
    if (j == 0) {
        zl[(size_t)n * 4 + 0] = make_float4(z[0], z[1], z[2], z[3]);
        zl[(size_t)n * 4 + 1] = make_float4(z[4], z[5], z[6], z[7]);
        zl[(size_t)n * 4 + 2] = make_float4(z[8], z[9], z[10], z[11]);
        zl[(size_t)n * 4 + 3] = make_float4(l0, l1, l2, l3);
    }
}

// Layer-1 epilogue: wave per node (12.5k blocks — high occupancy, coalesced
// writes).  fp32 out + packed bf16 rows + FOLDED layer-2 logits.
__global__ void epi1_kernel(const float4* __restrict__ zl,
                            const float* __restrict__ W1,
                            const float* __restrict__ b1,
                            const float4* __restrict__ ws2_4,
                            const float4* __restrict__ wd2_4,
                            float4* __restrict__ asrc4,
                            float4* __restrict__ adst4,
                            float* __restrict__ out,
                            unsigned short* __restrict__ out_pack, int N) {
    int node = (blockIdx.x * blockDim.x + threadIdx.x) >> 6;
    int c = threadIdx.x & 63;
    if (node >= N) return;
    float4 z0 = zl[(size_t)node * 4 + 0];
    float4 z1 = zl[(size_t)node * 4 + 1];
    float4 z2 = zl[(size_t)node * 4 + 2];
    float4 l4 = zl[(size_t)node * 4 + 3];
    float i0 = 0.25f / l4.x, i1 = 0.25f / l4.y;
    float i2 = 0.25f / l4.z, i3 = 0.25f / l4.w;
    float acc =
        (z0.x * W1[0 * HC +   0 + c] + z0.y * W1[1 * HC +   0 + c] + z0.z * W1[2 * HC +   0 + c]) * i0 +
        (z0.w * W1[0 * HC +  64 + c] + z1.x * W1[1 * HC +  64 + c] + z1.y * W1[2 * HC +  64 + c]) * i1 +
        (z1.z * W1[0 * HC + 128 + c] + z1.w * W1[1 * HC + 128 + c] + z2.x * W1[2 * HC + 128 + c]) * i2 +
        (z2.y * W1[0 * HC + 192 + c] + z2.z * W1[1 * HC + 192 + c] + z2.w * W1[2 * HC + 192 + c]) * i3;
    float v = acc + b1[c];
    v = v > 0.f ? v : expm1f(v);
    out[(size_t)node * CH + c] = v;
    out_pack[(size_t)node * CH + c] = (unsigned short)f2bf(v);
    float4 wsv = ws2_4[c], wdv = wd2_4[c];
    float4 sacc = make_float4(v * wsv.x, v * wsv.y, v * wsv.z, v * wsv.w);
    float4 dacc = make_float4(v * wdv.x, v * wdv.y, v * wdv.z, v * wdv.w);
    sacc = wave_sum4(sacc);
    dacc = wave_sum4(dacc);
    if (c == 0) { asrc4[node] = sacc; adst4[node] = dacc; }
}

// ---------------------------------------------------------------------------
// Input-space aggregation (layers 2/3): wave per dst node, 2 edges/iter
// (half-wave per edge, 2 k-columns per lane).  l accumulated in phase 2 from
// the LDS-broadcast exe.
__global__ void agg_kernel(const int* __restrict__ off,
                           const int* __restrict__ csr_src,
                           const unsigned short* __restrict__ xp,
                           const float4* __restrict__ asrc4,
                           const float4* __restrict__ adst4,
                           unsigned short* __restrict__ zb, int N) {
    __shared__ float4 exs[4][64];
    __shared__ unsigned int sss[4][64];
    int node = (blockIdx.x * blockDim.x + threadIdx.x) >> 6;
    int w = (threadIdx.x >> 6) & 3;
    int lane = threadIdx.x & 63;
    if (node >= N) return;
    int half = lane >> 5;          // which edge of the pair
    int lk = lane & 31;            // k-pair index: k = 2*lk, 2*lk+1
    int o0 = off[node], o1 = off[node + 1];
    int deg = o1 - o0;
    float4 ad = adst4[node];

    float l0 = 0.f, l1 = 0.f, l2 = 0.f, l3 = 0.f;
    float z[8];
#pragma unroll
    for (int q = 0; q < 8; ++q) z[q] = 0.f;
    const char* xpb2 = (const char*)xp + lk * 4;

    for (int base = 0; base < deg; base += 64) {
        int i = base + lane;
        int s = 0;
        float4 ev = make_float4(-INFINITY, -INFINITY, -INFINITY, -INFINITY);
        if (i < deg) {
            s = csr_src[o0 + i];
            float4 as = asrc4[s];
            ev.x = lrelu(as.x + ad.x);
            ev.y = lrelu(as.y + ad.y);
            ev.z = lrelu(as.z + ad.z);
            ev.w = lrelu(as.w + ad.w);
        }
        float4 ex;
        ex.x = __expf(ev.x);   // inactive lanes: exp(-inf) = 0
        ex.y = __expf(ev.y);
        ex.z = __expf(ev.z);
        ex.w = __expf(ev.w);
        exs[w][lane] = ex;
        sss[w][lane] = (unsigned)s * 128u;   // byte offset of row s in xp

        int cnt = min(64, deg - base);
        // 2 edges per iteration; tail edge (e==cnt) has exe==0.
#pragma unroll 2
        for (int e2 = 0; e2 < cnt; e2 += 2) {
            int e = e2 + half;
            unsigned soff = sss[w][e];       // 2-addr LDS broadcast (free)
            float4 exe = exs[w][e];
            l0 += exe.x; l1 += exe.y; l2 += exe.z; l3 += exe.w;
            unsigned xx = *(const unsigned*)(xpb2 + soff);
            float xk0 = bf2f((unsigned short)(xx & 0xffffu));
            float xk1 = bf2f((unsigned short)(xx >> 16));
            z[0] += exe.x * xk0; z[1] += exe.y * xk0;
            z[2] += exe.z * xk0; z[3] += exe.w * xk0;
            z[4] += exe.x * xk1; z[5] += exe.y * xk1;
            z[6] += exe.z * xk1; z[7] += exe.w * xk1;
        }
    }
    // combine even/odd edge chains across the two halves
#pragma unroll
    for (int q = 0; q < 8; ++q) z[q] += __shfl_xor(z[q], 32);
    l0 += __shfl_xor(l0, 32);
    l1 += __shfl_xor(l1, 32);
    l2 += __shfl_xor(l2, 32);
    l3 += __shfl_xor(l3, 32);

    float s0 = 0.25f / l0, s1 = 0.25f / l1, s2 = 0.25f / l2, s3 = 0.25f / l3;
    if (half == 0) {
        uint4 zo;   // zb[node][j], j=k*4+h: k0 -> j=8lk.., k1 -> j=8lk+4..
        zo.x = f2bf(z[0] * s0) | (f2bf(z[1] * s1) << 16);
        zo.y = f2bf(z[2] * s2) | (f2bf(z[3] * s3) << 16);
        zo.z = f2bf(z[4] * s0) | (f2bf(z[5] * s1) << 16);
        zo.w = f2bf(z[6] * s2) | (f2bf(z[7] * s3) << 16);
        *(uint4*)((char*)zb + (size_t)node * 512 + lk * 16) = zo;
    }
}

// ---------------------------------------------------------------------------
// MFMA post-aggregation GEMM (layers 2/3). A = zb (bf16 [n][j], j=k*4+h),
// B = Wb (bf16 [c][j]).  Layer-2 epilogue folds layer-3 logits; layer 3
// folds the final linear.
__global__ void gemm_mfma(const unsigned short* __restrict__ zb,
                          const unsigned short* __restrict__ Wb,
                          const float* __restrict__ bias,
                          const float* __restrict__ residual,
                          const float4* __restrict__ wsn4,
                          const float4* __restrict__ wdn4,
                          float4* __restrict__ asrc4,
                          float4* __restrict__ adst4,
                          const float* __restrict__ lin_w,
                          const float* __restrict__ lin_b,
                          float* __restrict__ out_f32,
                          unsigned short* __restrict__ out_pack,
                          float* __restrict__ out_final, int N) {
    int w = threadIdx.x >> 6;
    int lane = threadIdx.x & 63;
    int quad = lane >> 4, col = lane & 15;
    int nbase = blockIdx.x * 64 + w * 16;

    f32x4 zero4 = {0.f, 0.f, 0.f, 0.f};
    f32x4 acc[4];
#pragma unroll
    for (int t = 0; t < 4; ++t) acc[t] = zero4;

    const unsigned short* arow = zb + (size_t)(nbase + col) * HC + quad * 8;
#pragma unroll
    for (int q = 0; q < 8; ++q) {
        bf16x8 af = *(const bf16x8*)(arow + q * 32);
#pragma unroll
        for (int t = 0; t < 4; ++t) {
            const unsigned short* bp = Wb + (size_t)(t * 16 + col) * HC + q * 32 + quad * 8;
            bf16x8 bfrag = *(const bf16x8*)bp;
            acc[t] = __builtin_amdgcn_mfma_f32_16x16x32_bf16(af, bfrag, acc[t], 0, 0, 0);
        }
    }

    if (!out_final) {
        float vv[4][4];   // [t][r]
#pragma unroll
        for (int t = 0; t < 4; ++t) {
            int c = t * 16 + col;
            float bc = bias[c];
#pragma unroll
            for (int r = 0; r < 4; ++r) {
                int n = nbase + quad * 4 + r;
                float v = acc[t][r] + bc;
                v = v > 0.f ? v : expm1f(v);
                v += residual[(size_t)n * CH + c];
                vv[t][r] = v;
                if (n < N) {
                    out_f32[(size_t)n * CH + c] = v;
                    out_pack[(size_t)n * CH + c] = (unsigned short)f2bf(v);
                }
            }
        }
        float4 wsv[4], wdv[4];
#pragma unroll
        for (int t = 0; t < 4; ++t) { wsv[t] = wsn4[t * 16 + col]; wdv[t] = wdn4[t * 16 + col]; }
#pragma unroll
        for (int r = 0; r < 4; ++r) {
            int n = nbase + quad * 4 + r;
            float4 sa = make_float4(0.f, 0.f, 0.f, 0.f);
            float4 da = make_float4(0.f, 0.f, 0.f, 0.f);
#pragma unroll
            for (int t = 0; t < 4; ++t) {
                float v = vv[t][r];
                sa.x += v * wsv[t].x; sa.y += v * wsv[t].y;
                sa.z += v * wsv[t].z; sa.w += v * wsv[t].w;
                da.x += v * wdv[t].x; da.y += v * wdv[t].y;
                da.z += v * wdv[t].z; da.w += v * wdv[t].w;
            }
#pragma unroll
            for (int m = 8; m; m >>= 1) {
                sa.x += __shfl_xor(sa.x, m); sa.y += __shfl_xor(sa.y, m);
                sa.z += __shfl_xor(sa.z, m); sa.w += __shfl_xor(sa.w, m);
                da.x += __shfl_xor(da.x, m); da.y += __shfl_xor(da.y, m);
                da.z += __shfl_xor(da.z, m); da.w += __shfl_xor(da.w, m);
            }
            if (col == 0 && n < N) { asrc4[n] = sa; adst4[n] = da; }
        }
    } else {
        float lw[4], bb[4];
#pragma unroll
        for (int t = 0; t < 4; ++t) { lw[t] = lin_w[t * 16 + col]; bb[t] = bias[t * 16 + col]; }
#pragma unroll
        for (int r = 0; r < 4; ++r) {
            int n = nbase + quad * 4 + r;
            float ts = 0.f;
#pragma unroll
            for (int t = 0; t < 4; ++t) {
                float v = acc[t][r] + bb[t];
                v = v > 0.f ? v : expm1f(v);
                v += residual[(size_t)n * CH + (t * 16 + col)];
                ts += v * lw[t];
            }
            ts += __shfl_xor(ts, 1);
            ts += __shfl_xor(ts, 2);
            ts += __shfl_xor(ts, 4);
            ts += __shfl_xor(ts, 8);
            if (col == 0 && n < N) out_final[n] = ts + lin_b[0];
        }
    }
}

// ---------------------------------------------------------------------------
extern "C" void kernel_launch(void* const* d_in, const int* in_sizes, int n_in,
                              void* d_out, int out_size, void* d_ws, size_t ws_size,
                              hipStream_t stream) {
    const float* x      = (const float*)d_in[0];
    const int*   ei     = (const int*)  d_in[1];
    const float* W1     = (const float*)d_in[2];
    const float* a1s    = (const float*)d_in[3];
    const float* a1d    = (const float*)d_in[4];
    const float* b1     = (const float*)d_in[5];
    const float* W2     = (const float*)d_in[6];
    const float* a2s    = (const float*)d_in[7];
    const float* a2d    = (const float*)d_in[8];
    const float* b2     = (const float*)d_in[9];
    const float* W3     = (const float*)d_in[10];
    const float* a3s    = (const float*)d_in[11];
    const float* a3d    = (const float*)d_in[12];
    const float* b3     = (const float*)d_in[13];
    const float* lin_w  = (const float*)d_in[14];
    const float* lin_b  = (const float*)d_in[15];

    const int N = in_sizes[0] / 3;
    const int E = in_sizes[1] / 2;
    const int Et = E + N;
    const int* src = ei;
    const int* dst = ei + E;
    const float scale8 = 8.0f / (float)N;
    const int vec_ok = ((((size_t)src | (size_t)dst) & 15) == 0) ? 1 : 0;

    // ---- workspace layout (xq first for 16B alignment) ----
    float* xq_f   = (float*)d_ws;                         // N*4 (float4)
    unsigned short* zb  = (unsigned short*)(xq_f + (size_t)N * 4);  // N*256
    unsigned short* xpA = zb  + (size_t)N * HC;           // N*64
    unsigned short* xpB = xpA + (size_t)N * CH;           // N*64
    unsigned short* Wb2 = xpB + (size_t)N * CH;           // 16384
    unsigned short* Wb3 = Wb2 + 16384;                    // 16384
    float* bufA   = (float*)(Wb3 + 16384);                // N*64
    float* bufB   = bufA + (size_t)N * CH;                // N*64
    float* zl     = bufB + (size_t)N * CH;                // N*16
    float* asrc   = zl   + (size_t)N * 16;                // N*4
    float* adst   = asrc + (size_t)N * 4;                 // N*4
    float* ws1    = adst + (size_t)N * 4;                 // 16
    float* wd1    = ws1 + 16;                             // 16
    float* ws2    = wd1 + 16;                             // 256
    float* wd2    = ws2 + 256;                            // 256
    float* ws3    = wd2 + 256;                            // 256
    float* wd3    = ws3 + 256;                            // 256
    int* deg      = (int*)(wd3 + 256);                    // N
    int* off      = deg + N;                              // N+4
    int* bsum     = off + N + 4;                          // 1024
    int* slot     = bsum + 1024;                          // E
    int* csr_src  = slot + E;                             // Et

    const int B = 256;
    const int G = (N + 255) / 256;
    const int EB4 = (E + 3) / 4;                 // 4 edges per thread
    const int CB = (EB4 + B - 1) / B;

    // ---- CSR build + weight prep ----
    hipMemsetAsync(deg, 0, (size_t)N * sizeof(int), stream);
    count_kernel<<<CB * 8, B, 0, stream>>>(dst, E, vec_ok, scale8, deg, slot);
    scan_blocks<<<G, B, 0, stream>>>(deg, off, bsum, x, (float4*)xq_f, N);
    scan_add<<<G, B, 0, stream>>>(off, bsum, deg, csr_src, N);
    scatter_prep<<<CB + 133, B, 0, stream>>>(
        src, dst, slot, E, vec_ok, off, csr_src, CB,
        W1, a1s, a1d, ws1, wd1,
        W2, a2s, a2d, Wb2, ws2, wd2,
        W3, a3s, a3d, Wb3, ws3, wd3);

    int nwave_blocks = (N * 64 + B - 1) / B;   // wave per node
    int ngemm_blocks = (N + 63) / 64;          // 64 nodes per block

    // ---- Layer 1 (split: 4-lane agg + wave-node epilogue — measured best) ----
    fused1_kernel<<<(N * 4 + B - 1) / B, B, 0, stream>>>(
        off, csr_src, (const float4*)xq_f, ws1, wd1, (float4*)zl, N);
    epi1_kernel<<<nwave_blocks, B, 0, stream>>>(
        (const float4*)zl, W1, b1, (const float4*)ws2, (const float4*)wd2,
        (float4*)asrc, (float4*)adst, bufA, xpA, N);

    // ---- Layer 2 (gemm epilogue folds layer-3 logits) ----
    agg_kernel<<<nwave_blocks, B, 0, stream>>>(
        off, csr_src, xpA, (const float4*)asrc, (const float4*)adst,
        zb, N);
    gemm_mfma<<<ngemm_blocks, B, 0, stream>>>(
        zb, Wb2, b2, bufA, (const float4*)ws3, (const float4*)wd3,
        (float4*)asrc, (float4*)adst,
        nullptr, nullptr, bufB, xpB, nullptr, N);

    // ---- Layer 3 (+ fused final linear) ----
    agg_kernel<<<nwave_blocks, B, 0, stream>>>(
        off, csr_src, xpB, (const float4*)asrc, (const float4*)adst,
        zb, N);
    gemm_mfma<<<ngemm_blocks, B, 0, stream>>>(
        zb, Wb3, b3, bufB, nullptr, nullptr, nullptr, nullptr,
        lin_w, lin_b, nullptr, nullptr, (float*)d_out, N);
}